// Round 1
// baseline (2486.923 us; speedup 1.0000x reference)
//
#include <hip/hip_runtime.h>
#include <math.h>

// Model dims
#define NB 2
#define NL 1024
#define DM 768
#define DI 1536
#define DS 16
#define DCONV 4
#define DTR 48
#define NLAYERS 2
#define NTOK (NB*NL)   // 2048

__device__ __forceinline__ float softplus_f(float x) {
    return fmaxf(x, 0.f) + log1pf(expf(-fabsf(x)));
}

// ---------------- RMSNorm: one block per token ----------------
__global__ __launch_bounds__(256)
void rmsnorm_k(const float* __restrict__ in, const float* __restrict__ w,
               float* __restrict__ out)
{
    int t = blockIdx.x;
    int tid = threadIdx.x;
    const float* row = in + (size_t)t * DM;
    float v0 = row[tid], v1 = row[tid + 256], v2 = row[tid + 512];
    float ss = v0*v0 + v1*v1 + v2*v2;
    #pragma unroll
    for (int m = 32; m >= 1; m >>= 1) ss += __shfl_xor(ss, m, 64);
    __shared__ float red[4];
    if ((tid & 63) == 0) red[tid >> 6] = ss;
    __syncthreads();
    ss = red[0] + red[1] + red[2] + red[3];
    float sc = rsqrtf(ss * (1.f / DM) + 1e-5f);
    float* orow = out + (size_t)t * DM;
    orow[tid]       = v0 * sc * w[tid];
    orow[tid + 256] = v1 * sc * w[tid + 256];
    orow[tid + 512] = v2 * sc * w[tid + 512];
}

// ---------------- Final RMSNorm on last token only ----------------
__global__ __launch_bounds__(256)
void final_norm_k(const float* __restrict__ h, const float* __restrict__ w,
                  float* __restrict__ out)
{
    int b = blockIdx.x;
    int tid = threadIdx.x;
    const float* row = h + ((size_t)b * NL + (NL - 1)) * DM;
    float v0 = row[tid], v1 = row[tid + 256], v2 = row[tid + 512];
    float ss = v0*v0 + v1*v1 + v2*v2;
    #pragma unroll
    for (int m = 32; m >= 1; m >>= 1) ss += __shfl_xor(ss, m, 64);
    __shared__ float red[4];
    if ((tid & 63) == 0) red[tid >> 6] = ss;
    __syncthreads();
    ss = red[0] + red[1] + red[2] + red[3];
    float sc = rsqrtf(ss * (1.f / DM) + 1e-5f);
    float* orow = out + (size_t)b * DM;
    orow[tid]       = v0 * sc * w[tid];
    orow[tid + 256] = v1 * sc * w[tid + 256];
    orow[tid + 512] = v2 * sc * w[tid + 512];
}

// ---------------- Tiled NT GEMM: C[m,n] = sum_k A[m,k]*B[n,k] ----------------
// 64x64 tile, K-tile 16, 256 threads, 4x4 accum per thread.
// EPI: 0 = plain store; 1 = softplus(acc + bias[n]); 2 = acc + resid[m*N+n]
template<int EPI>
__global__ __launch_bounds__(256)
void gemm_nt(const float* __restrict__ A, const float* __restrict__ B,
             float* __restrict__ C, int M, int N, int K, int lda, int ldb,
             const float* __restrict__ bias, const float* __restrict__ resid)
{
    __shared__ float As[16][65];
    __shared__ float Bs[16][65];
    int tid = threadIdx.x;
    int tx = tid & 15, ty = tid >> 4;
    int bm = blockIdx.y * 64, bn = blockIdx.x * 64;
    float acc[4][4] = {};
    for (int k0 = 0; k0 < K; k0 += 16) {
        #pragma unroll
        for (int j = 0; j < 4; ++j) {
            As[tx][ty + 16*j] = A[(size_t)(bm + ty + 16*j) * lda + k0 + tx];
            Bs[tx][ty + 16*j] = B[(size_t)(bn + ty + 16*j) * ldb + k0 + tx];
        }
        __syncthreads();
        #pragma unroll
        for (int kk = 0; kk < 16; ++kk) {
            float a[4], b[4];
            #pragma unroll
            for (int i = 0; i < 4; ++i) a[i] = As[kk][ty*4 + i];
            #pragma unroll
            for (int j = 0; j < 4; ++j) b[j] = Bs[kk][tx*4 + j];
            #pragma unroll
            for (int i = 0; i < 4; ++i)
                #pragma unroll
                for (int j = 0; j < 4; ++j)
                    acc[i][j] = fmaf(a[i], b[j], acc[i][j]);
        }
        __syncthreads();
    }
    #pragma unroll
    for (int i = 0; i < 4; ++i) {
        int m = bm + ty*4 + i;
        int n = bn + tx*4;
        float4 v = make_float4(acc[i][0], acc[i][1], acc[i][2], acc[i][3]);
        if (EPI == 1) {
            v.x = softplus_f(v.x + bias[n + 0]);
            v.y = softplus_f(v.y + bias[n + 1]);
            v.z = softplus_f(v.z + bias[n + 2]);
            v.w = softplus_f(v.w + bias[n + 3]);
        } else if (EPI == 2) {
            const float4 r = *(const float4*)(resid + (size_t)m * N + n);
            v.x += r.x; v.y += r.y; v.z += r.z; v.w += r.w;
        }
        *(float4*)(C + (size_t)m * N + n) = v;
    }
}

// ---------------- Causal depthwise conv (width 4) + bias + SiLU ----------------
// xz: [T, 2*DI], xc = xz[:, :DI]. Output xconv [T, DI].
__global__ __launch_bounds__(256)
void conv_silu_k(const float* __restrict__ xz, const float* __restrict__ cw,
                 const float* __restrict__ cb, float* __restrict__ xconv)
{
    int t = blockIdx.x;              // 0..2047
    int l = t & (NL - 1), b = t >> 10;
    for (int d = threadIdx.x; d < DI; d += 256) {
        float acc = cb[d];
        #pragma unroll
        for (int k = 0; k < DCONV; ++k) {
            int ll = l - (DCONV - 1) + k;
            if (ll >= 0)
                acc = fmaf(xz[((size_t)(b * NL + ll)) * (2*DI) + d], cw[d*DCONV + k], acc);
        }
        float sg = 1.f / (1.f + __expf(-acc));
        xconv[(size_t)t * DI + d] = acc * sg;
    }
}

// ---------------- x_proj GEMV: xdbl[t,e] = sum_k xconv[t,k]*xp_w[e,k], e<80 ----------------
__global__ __launch_bounds__(320)
void xdbl_k(const float* __restrict__ xconv, const float* __restrict__ xp_w,
            float* __restrict__ xdbl)
{
    __shared__ float xs[DI];
    int t = blockIdx.x;
    int tid = threadIdx.x;
    for (int i = tid; i < DI; i += 320) xs[i] = xconv[(size_t)t * DI + i];
    __syncthreads();
    int e = tid >> 2, r = tid & 3;   // e in 0..79, 4 lanes per output
    const float* w = xp_w + (size_t)e * DI;
    float sum = 0.f;
    for (int k = r; k < DI; k += 4) sum = fmaf(xs[k], w[k], sum);
    sum += __shfl_xor(sum, 1, 64);
    sum += __shfl_xor(sum, 2, 64);
    if (r == 0) xdbl[(size_t)t * 80 + e] = sum;
}

// ---------------- Selective scan ----------------
// 16 lanes per channel (lane = state index n). Block = 256 thr = 16 channels.
// grid = (DI/16, B). dy is delta on input, overwritten with gated y.
__global__ __launch_bounds__(256)
void scan_k(float* dy,                          // [T, DI] delta in, y out (aliased)
            const float* __restrict__ xconv,    // [T, DI]
            const float* __restrict__ xz,       // [T, 2*DI] (z at +DI)
            const float* __restrict__ xdbl,     // [T, 80]  (B at +48, C at +64)
            const float* __restrict__ A_log,    // [DI, DS] layer base
            const float* __restrict__ Dp)       // [DI]
{
    int tid = threadIdx.x;
    int n = tid & 15;
    int dloc = tid >> 4;
    int d = blockIdx.x * 16 + dloc;
    int b = blockIdx.y;
    float a_coef = -__expf(A_log[d * DS + n]);   // A = -exp(A_log)
    float dpv = Dp[d];
    float s = 0.f;
    for (int l = 0; l < NL; ++l) {
        int t = b * NL + l;
        float dv  = dy[(size_t)t * DI + d];
        float xcv = xconv[(size_t)t * DI + d];
        float Bv  = xdbl[t * 80 + 48 + n];
        float Cv  = xdbl[t * 80 + 64 + n];
        s = __expf(dv * a_coef) * s + dv * Bv * xcv;
        float p = s * Cv;
        p += __shfl_xor(p, 1, 64);
        p += __shfl_xor(p, 2, 64);
        p += __shfl_xor(p, 4, 64);
        p += __shfl_xor(p, 8, 64);
        if (n == 0) {
            float zv = xz[(size_t)t * (2*DI) + DI + d];
            float y = p + xcv * dpv;
            y = y * zv / (1.f + __expf(-zv));    // y * silu(z)
            dy[(size_t)t * DI + d] = y;
        }
    }
}

extern "C" void kernel_launch(void* const* d_in, const int* in_sizes, int n_in,
                              void* d_out, int out_size, void* d_ws, size_t ws_size,
                              hipStream_t stream) {
    const float* x       = (const float*)d_in[0];
    const float* in_w    = (const float*)d_in[1];
    const float* conv_w  = (const float*)d_in[2];
    const float* conv_b  = (const float*)d_in[3];
    const float* xp_w    = (const float*)d_in[4];
    const float* dtp_w   = (const float*)d_in[5];
    const float* dtp_b   = (const float*)d_in[6];
    const float* A_log   = (const float*)d_in[7];
    const float* D_param = (const float*)d_in[8];
    const float* out_w   = (const float*)d_in[9];
    const float* norm_w  = (const float*)d_in[10];
    const float* fnorm_w = (const float*)d_in[11];
    float* out = (float*)d_out;

    float* ws    = (float*)d_ws;
    float* h     = ws;                          // [2048, 768]
    float* hn    = h     + (size_t)NTOK * DM;   // [2048, 768]
    float* xz    = hn    + (size_t)NTOK * DM;   // [2048, 3072]
    float* xconv = xz    + (size_t)NTOK * 2*DI; // [2048, 1536]
    float* xdbl  = xconv + (size_t)NTOK * DI;   // [2048, 80]
    float* dy    = xdbl  + (size_t)NTOK * 80;   // [2048, 1536] delta / y

    for (int layer = 0; layer < NLAYERS; ++layer) {
        const float* hin = (layer == 0) ? x : h;

        // 1. RMSNorm
        rmsnorm_k<<<NTOK, 256, 0, stream>>>(hin, norm_w + layer * DM, hn);

        // 2. in_proj: xz = hn @ in_w^T   [2048, 3072]
        gemm_nt<0><<<dim3((2*DI)/64, NTOK/64), 256, 0, stream>>>(
            hn, in_w + (size_t)layer * 2*DI * DM, xz,
            NTOK, 2*DI, DM, DM, DM, nullptr, nullptr);

        // 3. causal depthwise conv + SiLU
        conv_silu_k<<<NTOK, 256, 0, stream>>>(
            xz, conv_w + (size_t)layer * DI * DCONV, conv_b + (size_t)layer * DI, xconv);

        // 4. x_proj: xdbl = xconv @ xp_w^T   [2048, 80]
        xdbl_k<<<NTOK, 320, 0, stream>>>(
            xconv, xp_w + (size_t)layer * (DTR + 2*DS) * DI, xdbl);

        // 5. dt_proj + softplus: dy = softplus(dt @ dtp_w^T + dtp_b)  [2048, 1536]
        gemm_nt<1><<<dim3(DI/64, NTOK/64), 256, 0, stream>>>(
            xdbl, dtp_w + (size_t)layer * DI * DTR, dy,
            NTOK, DI, DTR, 80, DTR, dtp_b + (size_t)layer * DI, nullptr);

        // 6. selective scan + D skip + z gating (in-place dy -> y)
        scan_k<<<dim3(DI/16, NB), 256, 0, stream>>>(
            dy, xconv, xz, xdbl,
            A_log + (size_t)layer * DI * DS, D_param + (size_t)layer * DI);

        // 7. out_proj + residual: h = hin_resid + dy @ out_w^T   [2048, 768]
        gemm_nt<2><<<dim3(DM/64, NTOK/64), 256, 0, stream>>>(
            dy, out_w + (size_t)layer * DM * DI, h,
            NTOK, DM, DI, DI, DI, nullptr, hin);
    }

    // Final RMSNorm on last token of each batch
    final_norm_k<<<NB, 256, 0, stream>>>(h, fnorm_w, out);
}

// Round 2
// 1525.023 us; speedup vs baseline: 1.6307x; 1.6307x over previous
//
#include <hip/hip_runtime.h>
#include <math.h>

// Model dims
#define NB 2
#define NL 1024
#define DM 768
#define DI 1536
#define DS 16
#define DCONV 4
#define DTR 48
#define NLAYERS 2
#define NTOK (NB*NL)   // 2048

__device__ __forceinline__ float softplus_f(float x) {
    return fmaxf(x, 0.f) + log1pf(expf(-fabsf(x)));
}

// ---------------- RMSNorm: one block per token ----------------
__global__ __launch_bounds__(256)
void rmsnorm_k(const float* __restrict__ in, const float* __restrict__ w,
               float* __restrict__ out)
{
    int t = blockIdx.x;
    int tid = threadIdx.x;
    const float* row = in + (size_t)t * DM;
    float v0 = row[tid], v1 = row[tid + 256], v2 = row[tid + 512];
    float ss = v0*v0 + v1*v1 + v2*v2;
    #pragma unroll
    for (int m = 32; m >= 1; m >>= 1) ss += __shfl_xor(ss, m, 64);
    __shared__ float red[4];
    if ((tid & 63) == 0) red[tid >> 6] = ss;
    __syncthreads();
    ss = red[0] + red[1] + red[2] + red[3];
    float sc = rsqrtf(ss * (1.f / DM) + 1e-5f);
    float* orow = out + (size_t)t * DM;
    orow[tid]       = v0 * sc * w[tid];
    orow[tid + 256] = v1 * sc * w[tid + 256];
    orow[tid + 512] = v2 * sc * w[tid + 512];
}

// ---------------- Final RMSNorm on last token only ----------------
__global__ __launch_bounds__(256)
void final_norm_k(const float* __restrict__ h, const float* __restrict__ w,
                  float* __restrict__ out)
{
    int b = blockIdx.x;
    int tid = threadIdx.x;
    const float* row = h + ((size_t)b * NL + (NL - 1)) * DM;
    float v0 = row[tid], v1 = row[tid + 256], v2 = row[tid + 512];
    float ss = v0*v0 + v1*v1 + v2*v2;
    #pragma unroll
    for (int m = 32; m >= 1; m >>= 1) ss += __shfl_xor(ss, m, 64);
    __shared__ float red[4];
    if ((tid & 63) == 0) red[tid >> 6] = ss;
    __syncthreads();
    ss = red[0] + red[1] + red[2] + red[3];
    float sc = rsqrtf(ss * (1.f / DM) + 1e-5f);
    float* orow = out + (size_t)b * DM;
    orow[tid]       = v0 * sc * w[tid];
    orow[tid + 256] = v1 * sc * w[tid + 256];
    orow[tid + 512] = v2 * sc * w[tid + 512];
}

// ---------------- Tiled NT GEMM: C[m,n] = sum_k A[m,k]*B[n,k] ----------------
// 64x64 tile, K-tile 16, 256 threads, 4x4 accum per thread.
// EPI: 0 = plain store; 1 = softplus(acc + bias[n]); 2 = acc + resid[m*?+n]
template<int EPI>
__global__ __launch_bounds__(256)
void gemm_nt(const float* __restrict__ A, const float* __restrict__ B,
             float* __restrict__ C, int M, int N, int K, int lda, int ldb, int ldc,
             const float* __restrict__ bias, const float* __restrict__ resid)
{
    __shared__ float As[16][65];
    __shared__ float Bs[16][65];
    int tid = threadIdx.x;
    int tx = tid & 15, ty = tid >> 4;
    int bm = blockIdx.y * 64, bn = blockIdx.x * 64;
    float acc[4][4] = {};
    for (int k0 = 0; k0 < K; k0 += 16) {
        #pragma unroll
        for (int j = 0; j < 4; ++j) {
            As[tx][ty + 16*j] = A[(size_t)(bm + ty + 16*j) * lda + k0 + tx];
            Bs[tx][ty + 16*j] = B[(size_t)(bn + ty + 16*j) * ldb + k0 + tx];
        }
        __syncthreads();
        #pragma unroll
        for (int kk = 0; kk < 16; ++kk) {
            float a[4], b[4];
            #pragma unroll
            for (int i = 0; i < 4; ++i) a[i] = As[kk][ty*4 + i];
            #pragma unroll
            for (int j = 0; j < 4; ++j) b[j] = Bs[kk][tx*4 + j];
            #pragma unroll
            for (int i = 0; i < 4; ++i)
                #pragma unroll
                for (int j = 0; j < 4; ++j)
                    acc[i][j] = fmaf(a[i], b[j], acc[i][j]);
        }
        __syncthreads();
    }
    #pragma unroll
    for (int i = 0; i < 4; ++i) {
        int m = bm + ty*4 + i;
        int n = bn + tx*4;
        float4 v = make_float4(acc[i][0], acc[i][1], acc[i][2], acc[i][3]);
        if (EPI == 1) {
            v.x = softplus_f(v.x + bias[n + 0]);
            v.y = softplus_f(v.y + bias[n + 1]);
            v.z = softplus_f(v.z + bias[n + 2]);
            v.w = softplus_f(v.w + bias[n + 3]);
        } else if (EPI == 2) {
            const float4 r = *(const float4*)(resid + (size_t)m * ldc + n);
            v.x += r.x; v.y += r.y; v.z += r.z; v.w += r.w;
        }
        *(float4*)(C + (size_t)m * ldc + n) = v;
    }
}

// ---------------- Causal depthwise conv (width 4) + bias + SiLU ----------------
// xz: [T, 2*DI], xc = xz[:, :DI]. Output xconv [T, DI].
__global__ __launch_bounds__(256)
void conv_silu_k(const float* __restrict__ xz, const float* __restrict__ cw,
                 const float* __restrict__ cb, float* __restrict__ xconv)
{
    int t = blockIdx.x;              // 0..2047
    int l = t & (NL - 1), b = t >> 10;
    for (int d = threadIdx.x; d < DI; d += 256) {
        float acc = cb[d];
        #pragma unroll
        for (int k = 0; k < DCONV; ++k) {
            int ll = l - (DCONV - 1) + k;
            if (ll >= 0)
                acc = fmaf(xz[((size_t)(b * NL + ll)) * (2*DI) + d], cw[d*DCONV + k], acc);
        }
        float sg = 1.f / (1.f + __expf(-acc));
        xconv[(size_t)t * DI + d] = acc * sg;
    }
}

// ---------------- x_proj GEMV: xdbl[t,e] = sum_k xconv[t,k]*xp_w[e,k], e<80 ----------------
__global__ __launch_bounds__(320)
void xdbl_k(const float* __restrict__ xconv, const float* __restrict__ xp_w,
            float* __restrict__ xdbl)
{
    __shared__ float xs[DI];
    int t = blockIdx.x;
    int tid = threadIdx.x;
    for (int i = tid; i < DI; i += 320) xs[i] = xconv[(size_t)t * DI + i];
    __syncthreads();
    int e = tid >> 2, r = tid & 3;   // e in 0..79, 4 lanes per output
    const float* w = xp_w + (size_t)e * DI;
    float sum = 0.f;
    for (int k = r; k < DI; k += 4) sum = fmaf(xs[k], w[k], sum);
    sum += __shfl_xor(sum, 1, 64);
    sum += __shfl_xor(sum, 2, 64);
    if (r == 0) xdbl[(size_t)t * 80 + e] = sum;
}

// ---------------- Selective scan (pipelined, non-aliased) ----------------
// 16 lanes per channel (lane = state index n). Block = 256 thr = 16 channels.
// grid = (DI/16, B).
// delta  [T,DI]  read-only
// xconv  [T,DI]  read-only
// zin    = xz + DI  (stride 2*DI) read-only  (z half)
// yout   = xz       (stride 2*DI) write-only (dead xc half)
__global__ __launch_bounds__(256)
void scan_k(const float* __restrict__ delta,
            const float* __restrict__ xconv,
            const float* __restrict__ zin,
            float* __restrict__ yout,
            const float* __restrict__ xdbl,
            const float* __restrict__ A_log,
            const float* __restrict__ Dp)
{
    int tid = threadIdx.x;
    int n = tid & 15;
    int dloc = tid >> 4;
    int d = blockIdx.x * 16 + dloc;
    int b = blockIdx.y;
    float a_coef = -__expf(A_log[d * DS + n]);   // A = -exp(A_log)
    float dpv = Dp[d];
    float s = 0.f;
    const int base = b * NL;

    float dvA[8], xcA[8], BvA[8], CvA[8], zvA[8];
    float dvB[8], xcB[8], BvB[8], CvB[8], zvB[8];

    auto loadblk = [&](int j0, float (&dvb)[8], float (&xcb)[8],
                       float (&Bvb)[8], float (&Cvb)[8], float (&zvb)[8]) {
        #pragma unroll
        for (int k = 0; k < 8; ++k) {
            int t = base + j0 + k;
            dvb[k] = delta[(size_t)t * DI + d];
            xcb[k] = xconv[(size_t)t * DI + d];
            Bvb[k] = xdbl[t * 80 + 48 + n];
            Cvb[k] = xdbl[t * 80 + 64 + n];
            zvb[k] = zin[(size_t)t * (2*DI) + d];
        }
    };
    auto compblk = [&](int j0, float (&dvb)[8], float (&xcb)[8],
                       float (&Bvb)[8], float (&Cvb)[8], float (&zvb)[8]) {
        #pragma unroll
        for (int k = 0; k < 8; ++k) {
            float e = __expf(dvb[k] * a_coef);
            s = fmaf(e, s, dvb[k] * Bvb[k] * xcb[k]);
            float p = s * Cvb[k];
            p += __shfl_xor(p, 1, 64);
            p += __shfl_xor(p, 2, 64);
            p += __shfl_xor(p, 4, 64);
            p += __shfl_xor(p, 8, 64);
            if (n == 0) {
                float zv = zvb[k];
                float y = p + xcb[k] * dpv;
                y = y * zv / (1.f + __expf(-zv));    // y * silu(z)
                yout[(size_t)(base + j0 + k) * (2*DI) + d] = y;
            }
        }
    };

    loadblk(0, dvA, xcA, BvA, CvA, zvA);
    for (int j = 0; j < NL; j += 16) {
        loadblk(j + 8, dvB, xcB, BvB, CvB, zvB);
        compblk(j, dvA, xcA, BvA, CvA, zvA);
        if (j + 16 < NL)
            loadblk(j + 16, dvA, xcA, BvA, CvA, zvA);
        compblk(j + 8, dvB, xcB, BvB, CvB, zvB);
    }
}

extern "C" void kernel_launch(void* const* d_in, const int* in_sizes, int n_in,
                              void* d_out, int out_size, void* d_ws, size_t ws_size,
                              hipStream_t stream) {
    const float* x       = (const float*)d_in[0];
    const float* in_w    = (const float*)d_in[1];
    const float* conv_w  = (const float*)d_in[2];
    const float* conv_b  = (const float*)d_in[3];
    const float* xp_w    = (const float*)d_in[4];
    const float* dtp_w   = (const float*)d_in[5];
    const float* dtp_b   = (const float*)d_in[6];
    const float* A_log   = (const float*)d_in[7];
    const float* D_param = (const float*)d_in[8];
    const float* out_w   = (const float*)d_in[9];
    const float* norm_w  = (const float*)d_in[10];
    const float* fnorm_w = (const float*)d_in[11];
    float* out = (float*)d_out;

    float* ws    = (float*)d_ws;
    float* h     = ws;                          // [2048, 768]
    float* hn    = h     + (size_t)NTOK * DM;   // [2048, 768]
    float* xz    = hn    + (size_t)NTOK * DM;   // [2048, 3072]
    float* xconv = xz    + (size_t)NTOK * 2*DI; // [2048, 1536]
    float* xdbl  = xconv + (size_t)NTOK * DI;   // [2048, 80]
    float* dy    = xdbl  + (size_t)NTOK * 80;   // [2048, 1536] delta

    for (int layer = 0; layer < NLAYERS; ++layer) {
        const float* hin = (layer == 0) ? x : h;

        // 1. RMSNorm
        rmsnorm_k<<<NTOK, 256, 0, stream>>>(hin, norm_w + layer * DM, hn);

        // 2. in_proj: xz = hn @ in_w^T   [2048, 3072]
        gemm_nt<0><<<dim3((2*DI)/64, NTOK/64), 256, 0, stream>>>(
            hn, in_w + (size_t)layer * 2*DI * DM, xz,
            NTOK, 2*DI, DM, DM, DM, 2*DI, nullptr, nullptr);

        // 3. causal depthwise conv + SiLU
        conv_silu_k<<<NTOK, 256, 0, stream>>>(
            xz, conv_w + (size_t)layer * DI * DCONV, conv_b + (size_t)layer * DI, xconv);

        // 4. x_proj: xdbl = xconv @ xp_w^T   [2048, 80]
        xdbl_k<<<NTOK, 320, 0, stream>>>(
            xconv, xp_w + (size_t)layer * (DTR + 2*DS) * DI, xdbl);

        // 5. dt_proj + softplus: dy = softplus(dt @ dtp_w^T + dtp_b)  [2048, 1536]
        gemm_nt<1><<<dim3(DI/64, NTOK/64), 256, 0, stream>>>(
            xdbl, dtp_w + (size_t)layer * DI * DTR, dy,
            NTOK, DI, DTR, 80, DTR, DI, dtp_b + (size_t)layer * DI, nullptr);

        // 6. selective scan + D skip + z gating; y written into dead xc half of xz
        scan_k<<<dim3(DI/16, NB), 256, 0, stream>>>(
            dy, xconv, xz + DI, xz, xdbl,
            A_log + (size_t)layer * DI * DS, D_param + (size_t)layer * DI);

        // 7. out_proj + residual: h = hin_resid + y @ out_w^T   [2048, 768]
        //    y lives in xz with row stride 2*DI
        gemm_nt<2><<<dim3(DM/64, NTOK/64), 256, 0, stream>>>(
            xz, out_w + (size_t)layer * DM * DI, h,
            NTOK, DM, DI, 2*DI, DI, DM, nullptr, hin);
    }

    // Final RMSNorm on last token of each batch
    final_norm_k<<<NB, 256, 0, stream>>>(h, fnorm_w, out);
}

// Round 3
// 1029.899 us; speedup vs baseline: 2.4147x; 1.4808x over previous
//
#include <hip/hip_runtime.h>
#include <math.h>

// Model dims
#define NB 2
#define NL 1024
#define DM 768
#define DI 1536
#define DS 16
#define DCONV 4
#define DTR 48
#define NLAYERS 2
#define NTOK (NB*NL)   // 2048

#define CHUNK 128
#define SCAN_WAVES 8   // NL / CHUNK

__device__ __forceinline__ float softplus_f(float x) {
    return fmaxf(x, 0.f) + log1pf(expf(-fabsf(x)));
}

// ---------------- RMSNorm: one block per token ----------------
__global__ __launch_bounds__(256)
void rmsnorm_k(const float* __restrict__ in, const float* __restrict__ w,
               float* __restrict__ out)
{
    int t = blockIdx.x;
    int tid = threadIdx.x;
    const float* row = in + (size_t)t * DM;
    float v0 = row[tid], v1 = row[tid + 256], v2 = row[tid + 512];
    float ss = v0*v0 + v1*v1 + v2*v2;
    #pragma unroll
    for (int m = 32; m >= 1; m >>= 1) ss += __shfl_xor(ss, m, 64);
    __shared__ float red[4];
    if ((tid & 63) == 0) red[tid >> 6] = ss;
    __syncthreads();
    ss = red[0] + red[1] + red[2] + red[3];
    float sc = rsqrtf(ss * (1.f / DM) + 1e-5f);
    float* orow = out + (size_t)t * DM;
    orow[tid]       = v0 * sc * w[tid];
    orow[tid + 256] = v1 * sc * w[tid + 256];
    orow[tid + 512] = v2 * sc * w[tid + 512];
}

// ---------------- Final RMSNorm on last token only ----------------
__global__ __launch_bounds__(256)
void final_norm_k(const float* __restrict__ h, const float* __restrict__ w,
                  float* __restrict__ out)
{
    int b = blockIdx.x;
    int tid = threadIdx.x;
    const float* row = h + ((size_t)b * NL + (NL - 1)) * DM;
    float v0 = row[tid], v1 = row[tid + 256], v2 = row[tid + 512];
    float ss = v0*v0 + v1*v1 + v2*v2;
    #pragma unroll
    for (int m = 32; m >= 1; m >>= 1) ss += __shfl_xor(ss, m, 64);
    __shared__ float red[4];
    if ((tid & 63) == 0) red[tid >> 6] = ss;
    __syncthreads();
    ss = red[0] + red[1] + red[2] + red[3];
    float sc = rsqrtf(ss * (1.f / DM) + 1e-5f);
    float* orow = out + (size_t)b * DM;
    orow[tid]       = v0 * sc * w[tid];
    orow[tid + 256] = v1 * sc * w[tid + 256];
    orow[tid + 512] = v2 * sc * w[tid + 512];
}

// ---------------- Tiled NT GEMM: C[m,n] = sum_k A[m,k]*B[n,k] ----------------
// 64x64 tile, K-tile 16, 256 threads, 4x4 accum per thread.
// Pad 68 keeps rows 16B-aligned -> ds_read_b128 fragment loads.
// EPI: 0 = plain store; 1 = softplus(acc + bias[n]); 2 = acc + resid[m*?+n]
template<int EPI>
__global__ __launch_bounds__(256)
void gemm_nt(const float* __restrict__ A, const float* __restrict__ B,
             float* __restrict__ C, int M, int N, int K, int lda, int ldb, int ldc,
             const float* __restrict__ bias, const float* __restrict__ resid)
{
    __shared__ __align__(16) float As[16][68];
    __shared__ __align__(16) float Bs[16][68];
    int tid = threadIdx.x;
    int tx = tid & 15, ty = tid >> 4;
    int bm = blockIdx.y * 64, bn = blockIdx.x * 64;
    float acc[4][4] = {};
    for (int k0 = 0; k0 < K; k0 += 16) {
        #pragma unroll
        for (int j = 0; j < 4; ++j) {
            As[tx][ty + 16*j] = A[(size_t)(bm + ty + 16*j) * lda + k0 + tx];
            Bs[tx][ty + 16*j] = B[(size_t)(bn + ty + 16*j) * ldb + k0 + tx];
        }
        __syncthreads();
        #pragma unroll
        for (int kk = 0; kk < 16; ++kk) {
            float4 av = *(const float4*)&As[kk][ty*4];
            float4 bv = *(const float4*)&Bs[kk][tx*4];
            float a[4] = {av.x, av.y, av.z, av.w};
            float b[4] = {bv.x, bv.y, bv.z, bv.w};
            #pragma unroll
            for (int i = 0; i < 4; ++i)
                #pragma unroll
                for (int j = 0; j < 4; ++j)
                    acc[i][j] = fmaf(a[i], b[j], acc[i][j]);
        }
        __syncthreads();
    }
    #pragma unroll
    for (int i = 0; i < 4; ++i) {
        int m = bm + ty*4 + i;
        int n = bn + tx*4;
        float4 v = make_float4(acc[i][0], acc[i][1], acc[i][2], acc[i][3]);
        if (EPI == 1) {
            v.x = softplus_f(v.x + bias[n + 0]);
            v.y = softplus_f(v.y + bias[n + 1]);
            v.z = softplus_f(v.z + bias[n + 2]);
            v.w = softplus_f(v.w + bias[n + 3]);
        } else if (EPI == 2) {
            const float4 r = *(const float4*)(resid + (size_t)m * ldc + n);
            v.x += r.x; v.y += r.y; v.z += r.z; v.w += r.w;
        }
        *(float4*)(C + (size_t)m * ldc + n) = v;
    }
}

// ---------------- Causal depthwise conv (width 4) + bias + SiLU ----------------
__global__ __launch_bounds__(256)
void conv_silu_k(const float* __restrict__ xz, const float* __restrict__ cw,
                 const float* __restrict__ cb, float* __restrict__ xconv)
{
    int t = blockIdx.x;              // 0..2047
    int l = t & (NL - 1), b = t >> 10;
    for (int d = threadIdx.x; d < DI; d += 256) {
        float acc = cb[d];
        #pragma unroll
        for (int k = 0; k < DCONV; ++k) {
            int ll = l - (DCONV - 1) + k;
            if (ll >= 0)
                acc = fmaf(xz[((size_t)(b * NL + ll)) * (2*DI) + d], cw[d*DCONV + k], acc);
        }
        float sg = 1.f / (1.f + __expf(-acc));
        xconv[(size_t)t * DI + d] = acc * sg;
    }
}

// ---------------- x_proj GEMV ----------------
__global__ __launch_bounds__(320)
void xdbl_k(const float* __restrict__ xconv, const float* __restrict__ xp_w,
            float* __restrict__ xdbl)
{
    __shared__ float xs[DI];
    int t = blockIdx.x;
    int tid = threadIdx.x;
    for (int i = tid; i < DI; i += 320) xs[i] = xconv[(size_t)t * DI + i];
    __syncthreads();
    int e = tid >> 2, r = tid & 3;
    const float* w = xp_w + (size_t)e * DI;
    float sum = 0.f;
    for (int k = r; k < DI; k += 4) sum = fmaf(xs[k], w[k], sum);
    sum += __shfl_xor(sum, 1, 64);
    sum += __shfl_xor(sum, 2, 64);
    if (r == 0) xdbl[(size_t)t * 80 + e] = sum;
}

// ---------------- Selective scan: chunked parallel (8 chunks x 128) ----------------
// Block = 512 thr = 8 waves; block covers 4 channels x full L for one batch.
// Wave w owns time chunk [w*128, (w+1)*128). Lane: n = lane&15 (state),
// dloc = lane>>4 (channel within block).
// Pass A: local scan from 0, record decay product and final state per chunk.
// Combine: init_w = fold of predecessors (per-lane, <=7 fma).
// Pass B: re-run chunk from init_w, emit gated y.
__global__ __launch_bounds__(512)
void scan_k(const float* __restrict__ delta,   // [T,DI]
            const float* __restrict__ xconv,   // [T,DI]
            const float* __restrict__ zin,     // xz+DI, row stride 2*DI
            float* __restrict__ yout,          // xz,    row stride 2*DI
            const float* __restrict__ xdbl,    // [T,80] (B at +48, C at +64)
            const float* __restrict__ A_log,   // [DI,DS]
            const float* __restrict__ Dp)      // [DI]
{
    int tid  = threadIdx.x;
    int lane = tid & 63;
    int w    = tid >> 6;                  // wave = chunk id, 0..7
    int n    = lane & 15;
    int dloc = lane >> 4;                 // 0..3
    int d    = blockIdx.x * 4 + dloc;
    int b    = blockIdx.y;
    float a_coef = -__expf(A_log[d * DS + n]);
    float dpv = Dp[d];
    const int t0 = b * NL + w * CHUNK;

    __shared__ float lds_prod[SCAN_WAVES][64];
    __shared__ float lds_fin[SCAN_WAVES][64];

    // ---- Pass A: local scan, track running product of decay ----
    float s = 0.f, pe = 1.f;
    {
        float dvA[4], xcA[4], BvA[4], dvB[4], xcB[4], BvB[4];
        auto ld = [&](int j, float (&dv)[4], float (&xc)[4], float (&Bv)[4]) {
            #pragma unroll
            for (int k = 0; k < 4; ++k) {
                int t = t0 + j + k;
                dv[k] = delta[(size_t)t * DI + d];
                xc[k] = xconv[(size_t)t * DI + d];
                Bv[k] = xdbl[t * 80 + 48 + n];
            }
        };
        auto cp = [&](float (&dv)[4], float (&xc)[4], float (&Bv)[4]) {
            #pragma unroll
            for (int k = 0; k < 4; ++k) {
                float e = __expf(dv[k] * a_coef);
                pe *= e;
                s = fmaf(e, s, dv[k] * Bv[k] * xc[k]);
            }
        };
        ld(0, dvA, xcA, BvA);
        for (int j = 0; j < CHUNK; j += 8) {
            ld(j + 4, dvB, xcB, BvB);
            cp(dvA, xcA, BvA);
            if (j + 8 < CHUNK) ld(j + 8, dvA, xcA, BvA);
            cp(dvB, xcB, BvB);
        }
    }
    lds_prod[w][lane] = pe;
    lds_fin[w][lane]  = s;
    __syncthreads();

    // ---- Combine: fold predecessor chunk summaries (wave-uniform trip count) ----
    float init = 0.f;
    for (int v = 0; v < w; ++v)
        init = fmaf(lds_prod[v][lane], init, lds_fin[v][lane]);

    // ---- Pass B: re-run chunk from correct init, emit y ----
    s = init;
    {
        float dvA[4], xcA[4], BvA[4], CvA[4], zvA[4];
        float dvB[4], xcB[4], BvB[4], CvB[4], zvB[4];
        auto ld = [&](int j, float (&dv)[4], float (&xc)[4], float (&Bv)[4],
                      float (&Cv)[4], float (&zv)[4]) {
            #pragma unroll
            for (int k = 0; k < 4; ++k) {
                int t = t0 + j + k;
                dv[k] = delta[(size_t)t * DI + d];
                xc[k] = xconv[(size_t)t * DI + d];
                Bv[k] = xdbl[t * 80 + 48 + n];
                Cv[k] = xdbl[t * 80 + 64 + n];
                zv[k] = zin[(size_t)t * (2*DI) + d];
            }
        };
        auto cp = [&](int j, float (&dv)[4], float (&xc)[4], float (&Bv)[4],
                      float (&Cv)[4], float (&zv)[4]) {
            #pragma unroll
            for (int k = 0; k < 4; ++k) {
                float e = __expf(dv[k] * a_coef);
                s = fmaf(e, s, dv[k] * Bv[k] * xc[k]);
                float p = s * Cv[k];
                p += __shfl_xor(p, 1, 64);
                p += __shfl_xor(p, 2, 64);
                p += __shfl_xor(p, 4, 64);
                p += __shfl_xor(p, 8, 64);
                if (n == 0) {
                    float zv_ = zv[k];
                    float y = p + xc[k] * dpv;
                    y = y * zv_ / (1.f + __expf(-zv_));
                    yout[(size_t)(t0 + j + k) * (2*DI) + d] = y;
                }
            }
        };
        ld(0, dvA, xcA, BvA, CvA, zvA);
        for (int j = 0; j < CHUNK; j += 8) {
            ld(j + 4, dvB, xcB, BvB, CvB, zvB);
            cp(j, dvA, xcA, BvA, CvA, zvA);
            if (j + 8 < CHUNK) ld(j + 8, dvA, xcA, BvA, CvA, zvA);
            cp(j + 4, dvB, xcB, BvB, CvB, zvB);
        }
    }
}

extern "C" void kernel_launch(void* const* d_in, const int* in_sizes, int n_in,
                              void* d_out, int out_size, void* d_ws, size_t ws_size,
                              hipStream_t stream) {
    const float* x       = (const float*)d_in[0];
    const float* in_w    = (const float*)d_in[1];
    const float* conv_w  = (const float*)d_in[2];
    const float* conv_b  = (const float*)d_in[3];
    const float* xp_w    = (const float*)d_in[4];
    const float* dtp_w   = (const float*)d_in[5];
    const float* dtp_b   = (const float*)d_in[6];
    const float* A_log   = (const float*)d_in[7];
    const float* D_param = (const float*)d_in[8];
    const float* out_w   = (const float*)d_in[9];
    const float* norm_w  = (const float*)d_in[10];
    const float* fnorm_w = (const float*)d_in[11];
    float* out = (float*)d_out;

    float* ws    = (float*)d_ws;
    float* h     = ws;                          // [2048, 768]
    float* hn    = h     + (size_t)NTOK * DM;   // [2048, 768]
    float* xz    = hn    + (size_t)NTOK * DM;   // [2048, 3072]
    float* xconv = xz    + (size_t)NTOK * 2*DI; // [2048, 1536]
    float* xdbl  = xconv + (size_t)NTOK * DI;   // [2048, 80]
    float* dy    = xdbl  + (size_t)NTOK * 80;   // [2048, 1536] delta

    for (int layer = 0; layer < NLAYERS; ++layer) {
        const float* hin = (layer == 0) ? x : h;

        // 1. RMSNorm
        rmsnorm_k<<<NTOK, 256, 0, stream>>>(hin, norm_w + layer * DM, hn);

        // 2. in_proj: xz = hn @ in_w^T   [2048, 3072]
        gemm_nt<0><<<dim3((2*DI)/64, NTOK/64), 256, 0, stream>>>(
            hn, in_w + (size_t)layer * 2*DI * DM, xz,
            NTOK, 2*DI, DM, DM, DM, 2*DI, nullptr, nullptr);

        // 3. causal depthwise conv + SiLU
        conv_silu_k<<<NTOK, 256, 0, stream>>>(
            xz, conv_w + (size_t)layer * DI * DCONV, conv_b + (size_t)layer * DI, xconv);

        // 4. x_proj: xdbl = xconv @ xp_w^T   [2048, 80]
        xdbl_k<<<NTOK, 320, 0, stream>>>(
            xconv, xp_w + (size_t)layer * (DTR + 2*DS) * DI, xdbl);

        // 5. dt_proj + softplus: dy = softplus(dt @ dtp_w^T + dtp_b)  [2048, 1536]
        gemm_nt<1><<<dim3(DI/64, NTOK/64), 256, 0, stream>>>(
            xdbl, dtp_w + (size_t)layer * DI * DTR, dy,
            NTOK, DI, DTR, 80, DTR, DI, dtp_b + (size_t)layer * DI, nullptr);

        // 6. selective scan; y written into dead xc half of xz (stride 2*DI)
        scan_k<<<dim3(DI/4, NB), 512, 0, stream>>>(
            dy, xconv, xz + DI, xz, xdbl,
            A_log + (size_t)layer * DI * DS, D_param + (size_t)layer * DI);

        // 7. out_proj + residual: h = hin_resid + y @ out_w^T   [2048, 768]
        gemm_nt<2><<<dim3(DM/64, NTOK/64), 256, 0, stream>>>(
            xz, out_w + (size_t)layer * DM * DI, h,
            NTOK, DM, DI, 2*DI, DI, DM, nullptr, hin);
    }

    // Final RMSNorm on last token of each batch
    final_norm_k<<<NB, 256, 0, stream>>>(h, fnorm_w, out);
}

// Round 4
// 433.338 us; speedup vs baseline: 5.7390x; 2.3767x over previous
//
#include <hip/hip_runtime.h>
#include <math.h>

// Model dims
#define NB 2
#define NL 1024
#define DM 768
#define DI 1536
#define DS 16
#define DCONV 4
#define DTR 48
#define NLAYERS 2
#define NTOK (NB*NL)   // 2048

#define CHUNK 128
#define SCAN_WAVES 8   // NL / CHUNK

typedef unsigned short u16;
typedef __attribute__((ext_vector_type(8))) short bf16x8;
typedef __attribute__((ext_vector_type(4))) float f32x4;

__device__ __forceinline__ float softplus_f(float x) {
    return fmaxf(x, 0.f) + log1pf(expf(-fabsf(x)));
}
__device__ __forceinline__ u16 f2bf(float f) {
    union { float f; unsigned u; } x{f};
    unsigned r = x.u + 0x7fff + ((x.u >> 16) & 1);   // RNE
    return (u16)(r >> 16);
}
__device__ __forceinline__ float bf2f(u16 u) {
    union { unsigned u; float f; } x{(unsigned)u << 16};
    return x.f;
}

// ---------------- f32 -> bf16 conversion (weights) ----------------
__global__ __launch_bounds__(256)
void cvt_bf16_k(const float* __restrict__ in, u16* __restrict__ out, int n4)
{
    int i = blockIdx.x * 256 + threadIdx.x;
    if (i < n4) {
        float4 v = ((const float4*)in)[i];
        unsigned p0 = (unsigned)f2bf(v.x) | ((unsigned)f2bf(v.y) << 16);
        unsigned p1 = (unsigned)f2bf(v.z) | ((unsigned)f2bf(v.w) << 16);
        ((uint2*)out)[i] = make_uint2(p0, p1);
    }
}

// ---------------- RMSNorm: one block per token, bf16 out ----------------
__global__ __launch_bounds__(256)
void rmsnorm_k(const float* __restrict__ in, const float* __restrict__ w,
               u16* __restrict__ out)
{
    int t = blockIdx.x;
    int tid = threadIdx.x;
    const float* row = in + (size_t)t * DM;
    float v0 = row[tid], v1 = row[tid + 256], v2 = row[tid + 512];
    float ss = v0*v0 + v1*v1 + v2*v2;
    #pragma unroll
    for (int m = 32; m >= 1; m >>= 1) ss += __shfl_xor(ss, m, 64);
    __shared__ float red[4];
    if ((tid & 63) == 0) red[tid >> 6] = ss;
    __syncthreads();
    ss = red[0] + red[1] + red[2] + red[3];
    float sc = rsqrtf(ss * (1.f / DM) + 1e-5f);
    u16* orow = out + (size_t)t * DM;
    orow[tid]       = f2bf(v0 * sc * w[tid]);
    orow[tid + 256] = f2bf(v1 * sc * w[tid + 256]);
    orow[tid + 512] = f2bf(v2 * sc * w[tid + 512]);
}

// ---------------- Final RMSNorm on last token only (f32 out) ----------------
__global__ __launch_bounds__(256)
void final_norm_k(const float* __restrict__ h, const float* __restrict__ w,
                  float* __restrict__ out)
{
    int b = blockIdx.x;
    int tid = threadIdx.x;
    const float* row = h + ((size_t)b * NL + (NL - 1)) * DM;
    float v0 = row[tid], v1 = row[tid + 256], v2 = row[tid + 512];
    float ss = v0*v0 + v1*v1 + v2*v2;
    #pragma unroll
    for (int m = 32; m >= 1; m >>= 1) ss += __shfl_xor(ss, m, 64);
    __shared__ float red[4];
    if ((tid & 63) == 0) red[tid >> 6] = ss;
    __syncthreads();
    ss = red[0] + red[1] + red[2] + red[3];
    float sc = rsqrtf(ss * (1.f / DM) + 1e-5f);
    float* orow = out + (size_t)b * DM;
    orow[tid]       = v0 * sc * w[tid];
    orow[tid + 256] = v1 * sc * w[tid + 256];
    orow[tid + 512] = v2 * sc * w[tid + 512];
}

// ---------------- bf16 MFMA NT GEMM ----------------
// C[m,n] = sum_k A[m,k]*B[n,k], A:[M,K] bf16, B:[N,K] bf16, C f32.
// Both operands K-contiguous with row stride K. BK=32, 4 waves.
// LDS linear [BM+BN][32] bf16, staged via global_load_lds(16B) with
// chunk-rotate swizzle c' = (c + (row>>1)) & 3 (pre-swizzled source,
// swizzled fragment read) -> residual 2-way bank conflict (free).
// EPI: 0 = plain f32 store; 2 = + resid (f32, same ldc).
template<int BM, int BN, int WM, int WN, int EPI>
__global__ __launch_bounds__(256)
void mfma_nt(const u16* __restrict__ A, const u16* __restrict__ B,
             float* __restrict__ C, const float* __restrict__ resid,
             int K, int ldc)
{
    constexpr int BK = 32;
    constexpr int MR = BM / WM / 16;
    constexpr int NR = BN / WN / 16;
    constexpr int ALOADS = BM / 16;           // 1KB (16 rows x 64B) per load
    constexpr int BLOADS = BN / 16;
    constexpr int NLOADS = ALOADS + BLOADS;

    __shared__ alignas(16) u16 lds[2][(BM + BN) * BK];

    const int tid  = threadIdx.x;
    const int lane = tid & 63;
    const int w    = tid >> 6;
    const int bm   = blockIdx.y * BM;
    const int bn   = blockIdx.x * BN;
    const int wm0  = (w / WN) * (BM / WM);
    const int wn0  = (w % WN) * (BN / WN);

    f32x4 acc[MR][NR] = {};

    const int lrow4 = lane >> 2;   // row within 16-row load group
    const int lslot = lane & 3;    // 16B slot within 64B row segment

    auto stage = [&](int buf, int k0) {
        #pragma unroll
        for (int idx = 0; idx < NLOADS; ++idx) {
            if ((idx & 3) != w) continue;            // wave assignment
            const bool isA = idx < ALOADS;
            const int rowbase = (isA ? idx : idx - ALOADS) * 16;
            const int r = rowbase + lrow4;           // operand-local row
            const int c = (lslot - (r >> 1)) & 3;    // source chunk (pre-swizzle)
            const u16* src = (isA ? A + (size_t)(bm + r) * K
                                  : B + (size_t)(bn + r) * K) + k0 + c * 8;
            u16* dst = &lds[buf][((isA ? 0 : BM) + rowbase) * BK];
            __builtin_amdgcn_global_load_lds(
                (const __attribute__((address_space(1))) void*)src,
                (__attribute__((address_space(3))) void*)dst, 16, 0, 0);
        }
    };

    const int frow   = lane & 15;
    const int fchunk = lane >> 4;
    const int nk = K / BK;

    stage(0, 0);
    for (int kt = 0; kt < nk; ++kt) {
        __syncthreads();                              // drains vmcnt: buf[kt&1] ready
        if (kt + 1 < nk) stage((kt + 1) & 1, (kt + 1) * BK);
        const int buf = kt & 1;
        bf16x8 a[MR], b[NR];
        #pragma unroll
        for (int i = 0; i < MR; ++i) {
            int row = wm0 + i * 16 + frow;
            int ch = (fchunk + (row >> 1)) & 3;
            a[i] = *(const bf16x8*)&lds[buf][row * BK + ch * 8];
        }
        #pragma unroll
        for (int j = 0; j < NR; ++j) {
            int row = wn0 + j * 16 + frow;
            int ch = (fchunk + (row >> 1)) & 3;
            b[j] = *(const bf16x8*)&lds[buf][(BM + row) * BK + ch * 8];
        }
        #pragma unroll
        for (int i = 0; i < MR; ++i)
            #pragma unroll
            for (int j = 0; j < NR; ++j)
                acc[i][j] = __builtin_amdgcn_mfma_f32_16x16x32_bf16(
                                a[i], b[j], acc[i][j], 0, 0, 0);
    }

    // epilogue: D lane map col=lane&15, row=(lane>>4)*4+r (m89-verified)
    #pragma unroll
    for (int i = 0; i < MR; ++i) {
        #pragma unroll
        for (int j = 0; j < NR; ++j) {
            const int col  = bn + wn0 + j * 16 + (lane & 15);
            const int row0 = bm + wm0 + i * 16 + (lane >> 4) * 4;
            #pragma unroll
            for (int r = 0; r < 4; ++r) {
                float v = acc[i][j][r];
                size_t off = (size_t)(row0 + r) * ldc + col;
                if (EPI == 2) v += resid[off];
                C[off] = v;
            }
        }
    }
}

// ---------------- Causal depthwise conv (width 4) + bias + SiLU, bf16 out ----
__global__ __launch_bounds__(256)
void conv_silu_k(const float* __restrict__ xz, const float* __restrict__ cw,
                 const float* __restrict__ cb, u16* __restrict__ xconv)
{
    int t = blockIdx.x;              // 0..2047
    int l = t & (NL - 1), b = t >> 10;
    for (int d = threadIdx.x; d < DI; d += 256) {
        float acc = cb[d];
        #pragma unroll
        for (int k = 0; k < DCONV; ++k) {
            int ll = l - (DCONV - 1) + k;
            if (ll >= 0)
                acc = fmaf(xz[((size_t)(b * NL + ll)) * (2*DI) + d], cw[d*DCONV + k], acc);
        }
        float sg = 1.f / (1.f + __expf(-acc));
        xconv[(size_t)t * DI + d] = f2bf(acc * sg);
    }
}

// ---------------- dt_proj (f32 compute) + softplus, bf16 out ----------------
// C[m,n] = softplus(sum_k A[m,k]*B[n,k] + bias[n]); 64x64 tile, K-tile 16.
__global__ __launch_bounds__(256)
void gemm_sp_k(const float* __restrict__ A, const float* __restrict__ B,
               u16* __restrict__ C, int M, int N, int K, int lda, int ldb, int ldc,
               const float* __restrict__ bias)
{
    __shared__ __align__(16) float As[16][68];
    __shared__ __align__(16) float Bs[16][68];
    int tid = threadIdx.x;
    int tx = tid & 15, ty = tid >> 4;
    int bm = blockIdx.y * 64, bn = blockIdx.x * 64;
    float acc[4][4] = {};
    for (int k0 = 0; k0 < K; k0 += 16) {
        #pragma unroll
        for (int j = 0; j < 4; ++j) {
            As[tx][ty + 16*j] = A[(size_t)(bm + ty + 16*j) * lda + k0 + tx];
            Bs[tx][ty + 16*j] = B[(size_t)(bn + ty + 16*j) * ldb + k0 + tx];
        }
        __syncthreads();
        #pragma unroll
        for (int kk = 0; kk < 16; ++kk) {
            float4 av = *(const float4*)&As[kk][ty*4];
            float4 bv = *(const float4*)&Bs[kk][tx*4];
            float a[4] = {av.x, av.y, av.z, av.w};
            float b[4] = {bv.x, bv.y, bv.z, bv.w};
            #pragma unroll
            for (int i = 0; i < 4; ++i)
                #pragma unroll
                for (int j = 0; j < 4; ++j)
                    acc[i][j] = fmaf(a[i], b[j], acc[i][j]);
        }
        __syncthreads();
    }
    #pragma unroll
    for (int i = 0; i < 4; ++i) {
        int m = bm + ty*4 + i;
        int n = bn + tx*4;
        float vx = softplus_f(acc[i][0] + bias[n + 0]);
        float vy = softplus_f(acc[i][1] + bias[n + 1]);
        float vz = softplus_f(acc[i][2] + bias[n + 2]);
        float vw = softplus_f(acc[i][3] + bias[n + 3]);
        unsigned p0 = (unsigned)f2bf(vx) | ((unsigned)f2bf(vy) << 16);
        unsigned p1 = (unsigned)f2bf(vz) | ((unsigned)f2bf(vw) << 16);
        *(uint2*)(C + (size_t)m * ldc + n) = make_uint2(p0, p1);
    }
}

// ---------------- Selective scan: chunked parallel (8 chunks x 128) ----------
// Block = 512 thr = 8 waves; 4 channels x full L per block, one batch.
// delta/xconv bf16 [T,DI]; z f32 (stride 2*DI); y out bf16 [T,DI].
__global__ __launch_bounds__(512)
void scan_k(const u16* __restrict__ delta,
            const u16* __restrict__ xconv,
            const float* __restrict__ zin,
            u16* __restrict__ yout,
            const float* __restrict__ xdbl,    // [T,80] (B at +48, C at +64)
            const float* __restrict__ A_log,   // [DI,DS]
            const float* __restrict__ Dp)      // [DI]
{
    int tid  = threadIdx.x;
    int lane = tid & 63;
    int w    = tid >> 6;                  // wave = chunk id, 0..7
    int n    = lane & 15;
    int dloc = lane >> 4;                 // 0..3
    int d    = blockIdx.x * 4 + dloc;
    int b    = blockIdx.y;
    float a_coef = -__expf(A_log[d * DS + n]);
    float dpv = Dp[d];
    const int t0 = b * NL + w * CHUNK;

    __shared__ float lds_prod[SCAN_WAVES][64];
    __shared__ float lds_fin[SCAN_WAVES][64];

    // ---- Pass A: local scan, track running decay product ----
    float s = 0.f, pe = 1.f;
    {
        float dvA[4], xcA[4], BvA[4], dvB[4], xcB[4], BvB[4];
        auto ld = [&](int j, float (&dv)[4], float (&xc)[4], float (&Bv)[4]) {
            #pragma unroll
            for (int k = 0; k < 4; ++k) {
                int t = t0 + j + k;
                dv[k] = bf2f(delta[(size_t)t * DI + d]);
                xc[k] = bf2f(xconv[(size_t)t * DI + d]);
                Bv[k] = xdbl[t * 80 + 48 + n];
            }
        };
        auto cp = [&](float (&dv)[4], float (&xc)[4], float (&Bv)[4]) {
            #pragma unroll
            for (int k = 0; k < 4; ++k) {
                float e = __expf(dv[k] * a_coef);
                pe *= e;
                s = fmaf(e, s, dv[k] * Bv[k] * xc[k]);
            }
        };
        ld(0, dvA, xcA, BvA);
        for (int j = 0; j < CHUNK; j += 8) {
            ld(j + 4, dvB, xcB, BvB);
            cp(dvA, xcA, BvA);
            if (j + 8 < CHUNK) ld(j + 8, dvA, xcA, BvA);
            cp(dvB, xcB, BvB);
        }
    }
    lds_prod[w][lane] = pe;
    lds_fin[w][lane]  = s;
    __syncthreads();

    // ---- Combine predecessors ----
    float init = 0.f;
    for (int v = 0; v < w; ++v)
        init = fmaf(lds_prod[v][lane], init, lds_fin[v][lane]);

    // ---- Pass B: re-run from correct init, emit y ----
    s = init;
    {
        float dvA[4], xcA[4], BvA[4], CvA[4], zvA[4];
        float dvB[4], xcB[4], BvB[4], CvB[4], zvB[4];
        auto ld = [&](int j, float (&dv)[4], float (&xc)[4], float (&Bv)[4],
                      float (&Cv)[4], float (&zv)[4]) {
            #pragma unroll
            for (int k = 0; k < 4; ++k) {
                int t = t0 + j + k;
                dv[k] = bf2f(delta[(size_t)t * DI + d]);
                xc[k] = bf2f(xconv[(size_t)t * DI + d]);
                Bv[k] = xdbl[t * 80 + 48 + n];
                Cv[k] = xdbl[t * 80 + 64 + n];
                zv[k] = zin[(size_t)t * (2*DI) + d];
            }
        };
        auto cp = [&](int j, float (&dv)[4], float (&xc)[4], float (&Bv)[4],
                      float (&Cv)[4], float (&zv)[4]) {
            #pragma unroll
            for (int k = 0; k < 4; ++k) {
                float e = __expf(dv[k] * a_coef);
                s = fmaf(e, s, dv[k] * Bv[k] * xc[k]);
                float p = s * Cv[k];
                p += __shfl_xor(p, 1, 64);
                p += __shfl_xor(p, 2, 64);
                p += __shfl_xor(p, 4, 64);
                p += __shfl_xor(p, 8, 64);
                if (n == 0) {
                    float zv_ = zv[k];
                    float y = p + xc[k] * dpv;
                    y = y * zv_ / (1.f + __expf(-zv_));
                    yout[(size_t)(t0 + j + k) * DI + d] = f2bf(y);
                }
            }
        };
        ld(0, dvA, xcA, BvA, CvA, zvA);
        for (int j = 0; j < CHUNK; j += 8) {
            ld(j + 4, dvB, xcB, BvB, CvB, zvB);
            cp(j, dvA, xcA, BvA, CvA, zvA);
            if (j + 8 < CHUNK) ld(j + 8, dvA, xcA, BvA, CvA, zvA);
            cp(j + 4, dvB, xcB, BvB, CvB, zvB);
        }
    }
}

extern "C" void kernel_launch(void* const* d_in, const int* in_sizes, int n_in,
                              void* d_out, int out_size, void* d_ws, size_t ws_size,
                              hipStream_t stream) {
    const float* x       = (const float*)d_in[0];
    const float* in_w    = (const float*)d_in[1];
    const float* conv_w  = (const float*)d_in[2];
    const float* conv_b  = (const float*)d_in[3];
    const float* xp_w    = (const float*)d_in[4];
    const float* dtp_w   = (const float*)d_in[5];
    const float* dtp_b   = (const float*)d_in[6];
    const float* A_log   = (const float*)d_in[7];
    const float* D_param = (const float*)d_in[8];
    const float* out_w   = (const float*)d_in[9];
    const float* norm_w  = (const float*)d_in[10];
    const float* fnorm_w = (const float*)d_in[11];
    float* out = (float*)d_out;

    // ws layout (61.5 MB total)
    float* ws     = (float*)d_ws;
    float* h      = ws;                                 // [2048,768] f32
    float* xz     = h + (size_t)NTOK * DM;              // [2048,3072] f32
    float* xdbl   = xz + (size_t)NTOK * 2 * DI;         // [2048,80] f32
    u16*  hnb     = (u16*)(xdbl + (size_t)NTOK * 80);   // [2048,768] bf16
    u16*  xcbf    = hnb + (size_t)NTOK * DM;            // [2048,1536] bf16
    u16*  ybf     = xcbf + (size_t)NTOK * DI;           // [2048,1536] bf16
    u16*  dyb     = ybf + (size_t)NTOK * DI;            // [2048,1536] bf16 (delta)
    u16*  wbf_in  = dyb + (size_t)NTOK * DI;            // [3072,768] bf16
    u16*  wbf_xp  = wbf_in + (size_t)2 * DI * DM;       // [80,1536] bf16
    u16*  wbf_out = wbf_xp + (size_t)80 * DI;           // [768,1536] bf16

    for (int layer = 0; layer < NLAYERS; ++layer) {
        const float* hin = (layer == 0) ? x : h;

        // 0. weight conversion f32 -> bf16 (per layer, buffers reused)
        cvt_bf16_k<<<2304, 256, 0, stream>>>(in_w + (size_t)layer * 2*DI*DM, wbf_in, (2*DI*DM)/4);
        cvt_bf16_k<<<120, 256, 0, stream>>>(xp_w + (size_t)layer * 80*DI, wbf_xp, (80*DI)/4);
        cvt_bf16_k<<<1152, 256, 0, stream>>>(out_w + (size_t)layer * DM*DI, wbf_out, (DM*DI)/4);

        // 1. RMSNorm -> bf16
        rmsnorm_k<<<NTOK, 256, 0, stream>>>(hin, norm_w + layer * DM, hnb);

        // 2. in_proj (bf16 MFMA): xz = hn @ in_w^T  [2048,3072] f32
        mfma_nt<128, 128, 2, 2, 0><<<dim3((2*DI)/128, NTOK/128), 256, 0, stream>>>(
            hnb, wbf_in, xz, nullptr, DM, 2*DI);

        // 3. causal depthwise conv + SiLU -> bf16
        conv_silu_k<<<NTOK, 256, 0, stream>>>(
            xz, conv_w + (size_t)layer * DI * DCONV, conv_b + (size_t)layer * DI, xcbf);

        // 4. x_proj (bf16 MFMA): xdbl = xconv @ xp_w^T  [2048,80] f32
        mfma_nt<64, 80, 4, 1, 0><<<dim3(1, NTOK/64), 256, 0, stream>>>(
            xcbf, wbf_xp, xdbl, nullptr, DI, 80);

        // 5. dt_proj + softplus -> bf16 delta  [2048,1536]
        gemm_sp_k<<<dim3(DI/64, NTOK/64), 256, 0, stream>>>(
            xdbl, dtp_w + (size_t)layer * DI * DTR, dyb,
            NTOK, DI, DTR, 80, DTR, DI, dtp_b + (size_t)layer * DI);

        // 6. selective scan -> y bf16
        scan_k<<<dim3(DI/4, NB), 512, 0, stream>>>(
            dyb, xcbf, xz + DI, ybf, xdbl,
            A_log + (size_t)layer * DI * DS, D_param + (size_t)layer * DI);

        // 7. out_proj (bf16 MFMA) + residual: h = hin + y @ out_w^T  [2048,768]
        mfma_nt<64, 128, 2, 2, 2><<<dim3(DM/128, NTOK/64), 256, 0, stream>>>(
            ybf, wbf_out, h, hin, DI, DM);
    }

    // Final RMSNorm on last token of each batch
    final_norm_k<<<NB, 256, 0, stream>>>(h, fnorm_w, out);
}

// Round 5
// 314.702 us; speedup vs baseline: 7.9025x; 1.3770x over previous
//
#include <hip/hip_runtime.h>
#include <math.h>

// Model dims
#define NB 2
#define NL 1024
#define DM 768
#define DI 1536
#define DS 16
#define DCONV 4
#define DTR 48
#define NLAYERS 2
#define NTOK (NB*NL)   // 2048

#define NCHUNK 16
#define SCHUNK 64      // NL / NCHUNK

typedef unsigned short u16;
typedef __attribute__((ext_vector_type(8))) short bf16x8;
typedef __attribute__((ext_vector_type(4))) float f32x4;

__device__ __forceinline__ float softplus_f(float x) {
    return fmaxf(x, 0.f) + log1pf(expf(-fabsf(x)));
}
__device__ __forceinline__ u16 f2bf(float f) {
    union { float f; unsigned u; } x{f};
    unsigned r = x.u + 0x7fff + ((x.u >> 16) & 1);   // RNE
    return (u16)(r >> 16);
}
__device__ __forceinline__ float bf2f(u16 u) {
    union { unsigned u; float f; } x{(unsigned)u << 16};
    return x.f;
}

// Chunk-summary pool lives in the dead xc-half of xz (row stride 3072 f32,
// cols 0..1535). addr(k,b,ch,d,n) = ((b*16+ch)*48 + d>>5)*3072 + k*512 + (d&31)*16 + n
// k: 0=prod, 1=fin, 2=init.
__device__ __forceinline__ size_t pool_base(int b, int ch, int d) {
    return ((size_t)(b * NCHUNK + ch) * 48 + (d >> 5)) * 3072 + (size_t)(d & 31) * 16;
}

// ---------------- f32 -> bf16 conversion (weights) ----------------
__global__ __launch_bounds__(256)
void cvt_bf16_k(const float* __restrict__ in, u16* __restrict__ out, int n4)
{
    int i = blockIdx.x * 256 + threadIdx.x;
    if (i < n4) {
        float4 v = ((const float4*)in)[i];
        unsigned p0 = (unsigned)f2bf(v.x) | ((unsigned)f2bf(v.y) << 16);
        unsigned p1 = (unsigned)f2bf(v.z) | ((unsigned)f2bf(v.w) << 16);
        ((uint2*)out)[i] = make_uint2(p0, p1);
    }
}

// ---------------- RMSNorm: one block per token, bf16 out ----------------
__global__ __launch_bounds__(256)
void rmsnorm_k(const float* __restrict__ in, const float* __restrict__ w,
               u16* __restrict__ out)
{
    int t = blockIdx.x;
    int tid = threadIdx.x;
    const float* row = in + (size_t)t * DM;
    float v0 = row[tid], v1 = row[tid + 256], v2 = row[tid + 512];
    float ss = v0*v0 + v1*v1 + v2*v2;
    #pragma unroll
    for (int m = 32; m >= 1; m >>= 1) ss += __shfl_xor(ss, m, 64);
    __shared__ float red[4];
    if ((tid & 63) == 0) red[tid >> 6] = ss;
    __syncthreads();
    ss = red[0] + red[1] + red[2] + red[3];
    float sc = rsqrtf(ss * (1.f / DM) + 1e-5f);
    u16* orow = out + (size_t)t * DM;
    orow[tid]       = f2bf(v0 * sc * w[tid]);
    orow[tid + 256] = f2bf(v1 * sc * w[tid + 256]);
    orow[tid + 512] = f2bf(v2 * sc * w[tid + 512]);
}

// ---------------- Final RMSNorm on last token only (f32 out) ----------------
__global__ __launch_bounds__(256)
void final_norm_k(const float* __restrict__ h, const float* __restrict__ w,
                  float* __restrict__ out)
{
    int b = blockIdx.x;
    int tid = threadIdx.x;
    const float* row = h + ((size_t)b * NL + (NL - 1)) * DM;
    float v0 = row[tid], v1 = row[tid + 256], v2 = row[tid + 512];
    float ss = v0*v0 + v1*v1 + v2*v2;
    #pragma unroll
    for (int m = 32; m >= 1; m >>= 1) ss += __shfl_xor(ss, m, 64);
    __shared__ float red[4];
    if ((tid & 63) == 0) red[tid >> 6] = ss;
    __syncthreads();
    ss = red[0] + red[1] + red[2] + red[3];
    float sc = rsqrtf(ss * (1.f / DM) + 1e-5f);
    float* orow = out + (size_t)b * DM;
    orow[tid]       = v0 * sc * w[tid];
    orow[tid + 256] = v1 * sc * w[tid + 256];
    orow[tid + 512] = v2 * sc * w[tid + 512];
}

// ---------------- bf16 MFMA NT GEMM ----------------
template<int BM, int BN, int WM, int WN, int EPI>
__global__ __launch_bounds__(256)
void mfma_nt(const u16* __restrict__ A, const u16* __restrict__ B,
             float* __restrict__ C, const float* __restrict__ resid,
             int K, int ldc)
{
    constexpr int BK = 32;
    constexpr int MR = BM / WM / 16;
    constexpr int NR = BN / WN / 16;
    constexpr int ALOADS = BM / 16;
    constexpr int BLOADS = BN / 16;
    constexpr int NLOADS = ALOADS + BLOADS;

    __shared__ alignas(16) u16 lds[2][(BM + BN) * BK];

    const int tid  = threadIdx.x;
    const int lane = tid & 63;
    const int w    = tid >> 6;
    const int bm   = blockIdx.y * BM;
    const int bn   = blockIdx.x * BN;
    const int wm0  = (w / WN) * (BM / WM);
    const int wn0  = (w % WN) * (BN / WN);

    f32x4 acc[MR][NR] = {};

    const int lrow4 = lane >> 2;
    const int lslot = lane & 3;

    auto stage = [&](int buf, int k0) {
        #pragma unroll
        for (int idx = 0; idx < NLOADS; ++idx) {
            if ((idx & 3) != w) continue;
            const bool isA = idx < ALOADS;
            const int rowbase = (isA ? idx : idx - ALOADS) * 16;
            const int r = rowbase + lrow4;
            const int c = (lslot - (r >> 1)) & 3;
            const u16* src = (isA ? A + (size_t)(bm + r) * K
                                  : B + (size_t)(bn + r) * K) + k0 + c * 8;
            u16* dst = &lds[buf][((isA ? 0 : BM) + rowbase) * BK];
            __builtin_amdgcn_global_load_lds(
                (const __attribute__((address_space(1))) void*)src,
                (__attribute__((address_space(3))) void*)dst, 16, 0, 0);
        }
    };

    const int frow   = lane & 15;
    const int fchunk = lane >> 4;
    const int nk = K / BK;

    stage(0, 0);
    for (int kt = 0; kt < nk; ++kt) {
        __syncthreads();
        if (kt + 1 < nk) stage((kt + 1) & 1, (kt + 1) * BK);
        const int buf = kt & 1;
        bf16x8 a[MR], b[NR];
        #pragma unroll
        for (int i = 0; i < MR; ++i) {
            int row = wm0 + i * 16 + frow;
            int ch = (fchunk + (row >> 1)) & 3;
            a[i] = *(const bf16x8*)&lds[buf][row * BK + ch * 8];
        }
        #pragma unroll
        for (int j = 0; j < NR; ++j) {
            int row = wn0 + j * 16 + frow;
            int ch = (fchunk + (row >> 1)) & 3;
            b[j] = *(const bf16x8*)&lds[buf][(BM + row) * BK + ch * 8];
        }
        #pragma unroll
        for (int i = 0; i < MR; ++i)
            #pragma unroll
            for (int j = 0; j < NR; ++j)
                acc[i][j] = __builtin_amdgcn_mfma_f32_16x16x32_bf16(
                                a[i], b[j], acc[i][j], 0, 0, 0);
    }

    #pragma unroll
    for (int i = 0; i < MR; ++i) {
        #pragma unroll
        for (int j = 0; j < NR; ++j) {
            const int col  = bn + wn0 + j * 16 + (lane & 15);
            const int row0 = bm + wm0 + i * 16 + (lane >> 4) * 4;
            #pragma unroll
            for (int r = 0; r < 4; ++r) {
                float v = acc[i][j][r];
                size_t off = (size_t)(row0 + r) * ldc + col;
                if (EPI == 2) v += resid[off];
                C[off] = v;
            }
        }
    }
}

// ---------------- Causal depthwise conv (width 4) + bias + SiLU, bf16 out ----
__global__ __launch_bounds__(256)
void conv_silu_k(const float* __restrict__ xz, const float* __restrict__ cw,
                 const float* __restrict__ cb, u16* __restrict__ xconv)
{
    int t = blockIdx.x;
    int l = t & (NL - 1), b = t >> 10;
    for (int d = threadIdx.x; d < DI; d += 256) {
        float acc = cb[d];
        #pragma unroll
        for (int k = 0; k < DCONV; ++k) {
            int ll = l - (DCONV - 1) + k;
            if (ll >= 0)
                acc = fmaf(xz[((size_t)(b * NL + ll)) * (2*DI) + d], cw[d*DCONV + k], acc);
        }
        float sg = 1.f / (1.f + __expf(-acc));
        xconv[(size_t)t * DI + d] = f2bf(acc * sg);
    }
}

// ---------------- dt_proj (f32 compute) + softplus, bf16 out ----------------
__global__ __launch_bounds__(256)
void gemm_sp_k(const float* __restrict__ A, const float* __restrict__ B,
               u16* __restrict__ C, int M, int N, int K, int lda, int ldb, int ldc,
               const float* __restrict__ bias)
{
    __shared__ __align__(16) float As[16][68];
    __shared__ __align__(16) float Bs[16][68];
    int tid = threadIdx.x;
    int tx = tid & 15, ty = tid >> 4;
    int bm = blockIdx.y * 64, bn = blockIdx.x * 64;
    float acc[4][4] = {};
    for (int k0 = 0; k0 < K; k0 += 16) {
        #pragma unroll
        for (int j = 0; j < 4; ++j) {
            As[tx][ty + 16*j] = A[(size_t)(bm + ty + 16*j) * lda + k0 + tx];
            Bs[tx][ty + 16*j] = B[(size_t)(bn + ty + 16*j) * ldb + k0 + tx];
        }
        __syncthreads();
        #pragma unroll
        for (int kk = 0; kk < 16; ++kk) {
            float4 av = *(const float4*)&As[kk][ty*4];
            float4 bv = *(const float4*)&Bs[kk][tx*4];
            float a[4] = {av.x, av.y, av.z, av.w};
            float b[4] = {bv.x, bv.y, bv.z, bv.w};
            #pragma unroll
            for (int i = 0; i < 4; ++i)
                #pragma unroll
                for (int j = 0; j < 4; ++j)
                    acc[i][j] = fmaf(a[i], b[j], acc[i][j]);
        }
        __syncthreads();
    }
    #pragma unroll
    for (int i = 0; i < 4; ++i) {
        int m = bm + ty*4 + i;
        int n = bn + tx*4;
        float vx = softplus_f(acc[i][0] + bias[n + 0]);
        float vy = softplus_f(acc[i][1] + bias[n + 1]);
        float vz = softplus_f(acc[i][2] + bias[n + 2]);
        float vw = softplus_f(acc[i][3] + bias[n + 3]);
        unsigned p0 = (unsigned)f2bf(vx) | ((unsigned)f2bf(vy) << 16);
        unsigned p1 = (unsigned)f2bf(vz) | ((unsigned)f2bf(vw) << 16);
        *(uint2*)(C + (size_t)m * ldc + n) = make_uint2(p0, p1);
    }
}

// ---------------- Scan pass A: per-chunk local scan -> (prod, fin) ----------
// Block = 64 thr (1 wave) = 64 channels. Grid (DI/64, NB, NCHUNK).
// Thread: channel d, all 16 states in registers.
__global__ __launch_bounds__(64)
void scan_part_k(const u16* __restrict__ delta, const u16* __restrict__ xconv,
                 const float* __restrict__ xdbl, const float* __restrict__ A_log,
                 float* __restrict__ pool)
{
    int lane = threadIdx.x;
    int d = blockIdx.x * 64 + lane;
    int b = blockIdx.y, ch = blockIdx.z;
    int t0 = b * NL + ch * SCHUNK;

    __shared__ float bs[SCHUNK][16];      // B[t,n] staging, 4KB
    for (int s = lane; s < SCHUNK * 4; s += 64) {
        int st = s >> 2, q = s & 3;
        *(float4*)&bs[st][q * 4] =
            *(const float4*)(xdbl + (size_t)(t0 + st) * 80 + 48 + q * 4);
    }
    __syncthreads();

    float a[DS];
    {
        const float* al = A_log + (size_t)d * DS;
        #pragma unroll
        for (int n = 0; n < DS; ++n) a[n] = -__expf(al[n]);
    }
    float s_[DS], pe[DS];
    #pragma unroll
    for (int n = 0; n < DS; ++n) { s_[n] = 0.f; pe[n] = 1.f; }

    float dvA[4], xcA[4], dvB[4], xcB[4];
    auto ld = [&](int j, float (&dv)[4], float (&xc)[4]) {
        #pragma unroll
        for (int k = 0; k < 4; ++k) {
            int t = t0 + j + k;
            dv[k] = bf2f(delta[(size_t)t * DI + d]);
            xc[k] = bf2f(xconv[(size_t)t * DI + d]);
        }
    };
    auto cp = [&](int j, float (&dv)[4], float (&xc)[4]) {
        #pragma unroll
        for (int k = 0; k < 4; ++k) {
            float u = dv[k] * xc[k];
            float bb[16];
            *(float4*)&bb[0]  = *(const float4*)&bs[j + k][0];
            *(float4*)&bb[4]  = *(const float4*)&bs[j + k][4];
            *(float4*)&bb[8]  = *(const float4*)&bs[j + k][8];
            *(float4*)&bb[12] = *(const float4*)&bs[j + k][12];
            #pragma unroll
            for (int n = 0; n < DS; ++n) {
                float e = __expf(dv[k] * a[n]);
                pe[n] *= e;
                s_[n] = fmaf(e, s_[n], u * bb[n]);
            }
        }
    };
    ld(0, dvA, xcA);
    for (int j = 0; j < SCHUNK; j += 8) {
        ld(j + 4, dvB, xcB);
        cp(j, dvA, xcA);
        if (j + 8 < SCHUNK) ld(j + 8, dvA, xcA);
        cp(j + 4, dvB, xcB);
    }

    size_t base = pool_base(b, ch, d);
    #pragma unroll
    for (int q = 0; q < 4; ++q) {
        *(float4*)(pool + base + q*4) =
            make_float4(pe[q*4], pe[q*4+1], pe[q*4+2], pe[q*4+3]);
        *(float4*)(pool + base + 512 + q*4) =
            make_float4(s_[q*4], s_[q*4+1], s_[q*4+2], s_[q*4+3]);
    }
}

// ---------------- Scan prefix: fold chunk summaries -> init states ----------
// Thread per (d,n). Grid (DI*DS/256, NB).
__global__ __launch_bounds__(256)
void scan_prefix_k(float* __restrict__ pool)
{
    int dn = blockIdx.x * 256 + threadIdx.x;
    int b = blockIdx.y;
    int d = dn >> 4, n = dn & 15;
    float run = 0.f;
    for (int ch = 0; ch < NCHUNK; ++ch) {
        size_t base = pool_base(b, ch, d) + n;
        float p = pool[base];
        float f = pool[base + 512];
        pool[base + 1024] = run;
        run = fmaf(p, run, f);
    }
}

// ---------------- Scan pass B: re-run from init, emit gated y ---------------
__global__ __launch_bounds__(64)
void scan_emit_k(const u16* __restrict__ delta, const u16* __restrict__ xconv,
                 const float* __restrict__ zin,   // xz + DI, row stride 2*DI
                 u16* __restrict__ yout,          // [T, DI] bf16
                 const float* __restrict__ xdbl, const float* __restrict__ A_log,
                 const float* __restrict__ Dp, const float* __restrict__ pool)
{
    int lane = threadIdx.x;
    int d = blockIdx.x * 64 + lane;
    int b = blockIdx.y, ch = blockIdx.z;
    int t0 = b * NL + ch * SCHUNK;

    __shared__ float bcs[SCHUNK][32];     // B|C staging, 8KB
    for (int s = lane; s < SCHUNK * 8; s += 64) {
        int st = s >> 3, q = s & 7;
        *(float4*)&bcs[st][q * 4] =
            *(const float4*)(xdbl + (size_t)(t0 + st) * 80 + 48 + q * 4);
    }
    __syncthreads();

    float a[DS];
    {
        const float* al = A_log + (size_t)d * DS;
        #pragma unroll
        for (int n = 0; n < DS; ++n) a[n] = -__expf(al[n]);
    }
    float dpv = Dp[d];

    float s_[DS];
    {
        size_t base = pool_base(b, ch, d) + 1024;
        #pragma unroll
        for (int q = 0; q < 4; ++q) {
            float4 v = *(const float4*)(pool + base + q*4);
            s_[q*4] = v.x; s_[q*4+1] = v.y; s_[q*4+2] = v.z; s_[q*4+3] = v.w;
        }
    }

    float dvA[4], xcA[4], zvA[4], dvB[4], xcB[4], zvB[4];
    auto ld = [&](int j, float (&dv)[4], float (&xc)[4], float (&zv)[4]) {
        #pragma unroll
        for (int k = 0; k < 4; ++k) {
            int t = t0 + j + k;
            dv[k] = bf2f(delta[(size_t)t * DI + d]);
            xc[k] = bf2f(xconv[(size_t)t * DI + d]);
            zv[k] = zin[(size_t)t * (2*DI) + d];
        }
    };
    auto cp = [&](int j, float (&dv)[4], float (&xc)[4], float (&zv)[4]) {
        #pragma unroll
        for (int k = 0; k < 4; ++k) {
            float u = dv[k] * xc[k];
            float bb[16], cc[16];
            #pragma unroll
            for (int q = 0; q < 4; ++q) {
                *(float4*)&bb[q*4] = *(const float4*)&bcs[j + k][q*4];
                *(float4*)&cc[q*4] = *(const float4*)&bcs[j + k][16 + q*4];
            }
            float y0 = 0.f;
            #pragma unroll
            for (int n = 0; n < DS; ++n) {
                float e = __expf(dv[k] * a[n]);
                s_[n] = fmaf(e, s_[n], u * bb[n]);
                y0 = fmaf(s_[n], cc[n], y0);
            }
            float zv_ = zv[k];
            float y = y0 + xc[k] * dpv;
            y = y * zv_ / (1.f + __expf(-zv_));
            yout[(size_t)(t0 + j + k) * DI + d] = f2bf(y);
        }
    };
    ld(0, dvA, xcA, zvA);
    for (int j = 0; j < SCHUNK; j += 8) {
        ld(j + 4, dvB, xcB, zvB);
        cp(j, dvA, xcA, zvA);
        if (j + 8 < SCHUNK) ld(j + 8, dvA, xcA, zvA);
        cp(j + 4, dvB, xcB, zvB);
    }
}

extern "C" void kernel_launch(void* const* d_in, const int* in_sizes, int n_in,
                              void* d_out, int out_size, void* d_ws, size_t ws_size,
                              hipStream_t stream) {
    const float* x       = (const float*)d_in[0];
    const float* in_w    = (const float*)d_in[1];
    const float* conv_w  = (const float*)d_in[2];
    const float* conv_b  = (const float*)d_in[3];
    const float* xp_w    = (const float*)d_in[4];
    const float* dtp_w   = (const float*)d_in[5];
    const float* dtp_b   = (const float*)d_in[6];
    const float* A_log   = (const float*)d_in[7];
    const float* D_param = (const float*)d_in[8];
    const float* out_w   = (const float*)d_in[9];
    const float* norm_w  = (const float*)d_in[10];
    const float* fnorm_w = (const float*)d_in[11];
    float* out = (float*)d_out;

    // ws layout (61.5 MB total)
    float* ws     = (float*)d_ws;
    float* h      = ws;                                 // [2048,768] f32
    float* xz     = h + (size_t)NTOK * DM;              // [2048,3072] f32 (xc half doubles as scan pool)
    float* xdbl   = xz + (size_t)NTOK * 2 * DI;         // [2048,80] f32
    u16*  hnb     = (u16*)(xdbl + (size_t)NTOK * 80);   // [2048,768] bf16
    u16*  xcbf    = hnb + (size_t)NTOK * DM;            // [2048,1536] bf16
    u16*  ybf     = xcbf + (size_t)NTOK * DI;           // [2048,1536] bf16
    u16*  dyb     = ybf + (size_t)NTOK * DI;            // [2048,1536] bf16 (delta)
    u16*  wbf_in  = dyb + (size_t)NTOK * DI;            // [3072,768] bf16
    u16*  wbf_xp  = wbf_in + (size_t)2 * DI * DM;       // [80,1536] bf16
    u16*  wbf_out = wbf_xp + (size_t)80 * DI;           // [768,1536] bf16

    for (int layer = 0; layer < NLAYERS; ++layer) {
        const float* hin = (layer == 0) ? x : h;
        const float* Alog_l = A_log + (size_t)layer * DI * DS;

        // 0. weight conversion f32 -> bf16
        cvt_bf16_k<<<2304, 256, 0, stream>>>(in_w + (size_t)layer * 2*DI*DM, wbf_in, (2*DI*DM)/4);
        cvt_bf16_k<<<120, 256, 0, stream>>>(xp_w + (size_t)layer * 80*DI, wbf_xp, (80*DI)/4);
        cvt_bf16_k<<<1152, 256, 0, stream>>>(out_w + (size_t)layer * DM*DI, wbf_out, (DM*DI)/4);

        // 1. RMSNorm -> bf16
        rmsnorm_k<<<NTOK, 256, 0, stream>>>(hin, norm_w + layer * DM, hnb);

        // 2. in_proj (bf16 MFMA): xz = hn @ in_w^T  [2048,3072] f32
        mfma_nt<128, 128, 2, 2, 0><<<dim3((2*DI)/128, NTOK/128), 256, 0, stream>>>(
            hnb, wbf_in, xz, nullptr, DM, 2*DI);

        // 3. causal depthwise conv + SiLU -> bf16
        conv_silu_k<<<NTOK, 256, 0, stream>>>(
            xz, conv_w + (size_t)layer * DI * DCONV, conv_b + (size_t)layer * DI, xcbf);

        // 4. x_proj (bf16 MFMA): xdbl = xconv @ xp_w^T  [2048,80] f32
        mfma_nt<64, 80, 4, 1, 0><<<dim3(1, NTOK/64), 256, 0, stream>>>(
            xcbf, wbf_xp, xdbl, nullptr, DI, 80);

        // 5. dt_proj + softplus -> bf16 delta  [2048,1536]
        gemm_sp_k<<<dim3(DI/64, NTOK/64), 256, 0, stream>>>(
            xdbl, dtp_w + (size_t)layer * DI * DTR, dyb,
            NTOK, DI, DTR, 80, DTR, DI, dtp_b + (size_t)layer * DI);

        // 6. selective scan: part -> prefix -> emit (pool in dead xc-half of xz)
        scan_part_k<<<dim3(DI/64, NB, NCHUNK), 64, 0, stream>>>(
            dyb, xcbf, xdbl, Alog_l, xz);
        scan_prefix_k<<<dim3((DI*DS)/256, NB), 256, 0, stream>>>(xz);
        scan_emit_k<<<dim3(DI/64, NB, NCHUNK), 64, 0, stream>>>(
            dyb, xcbf, xz + DI, ybf, xdbl, Alog_l,
            D_param + (size_t)layer * DI, xz);

        // 7. out_proj (bf16 MFMA) + residual: h = hin + y @ out_w^T  [2048,768]
        mfma_nt<64, 128, 2, 2, 2><<<dim3(DM/128, NTOK/64), 256, 0, stream>>>(
            ybf, wbf_out, h, hin, DI, DM);
    }

    // Final RMSNorm on last token of each batch
    final_norm_k<<<NB, 256, 0, stream>>>(h, fnorm_w, out);
}

// Round 6
// 296.066 us; speedup vs baseline: 8.3999x; 1.0629x over previous
//
#include <hip/hip_runtime.h>
#include <math.h>

// Model dims
#define NB 2
#define NL 1024
#define DM 768
#define DI 1536
#define DS 16
#define DCONV 4
#define DTR 48
#define NLAYERS 2
#define NTOK (NB*NL)   // 2048

#define NCHUNK 32
#define SCHUNK 32      // NL / NCHUNK

typedef unsigned short u16;
typedef __attribute__((ext_vector_type(8))) short bf16x8;
typedef __attribute__((ext_vector_type(4))) float f32x4;

__device__ __forceinline__ float softplus_f(float x) {
    return fmaxf(x, 0.f) + log1pf(expf(-fabsf(x)));
}
__device__ __forceinline__ u16 f2bf(float f) {
    union { float f; unsigned u; } x{f};
    unsigned r = x.u + 0x7fff + ((x.u >> 16) & 1);   // RNE
    return (u16)(r >> 16);
}
__device__ __forceinline__ float bf2f(u16 u) {
    union { unsigned u; float f; } x{(unsigned)u << 16};
    return x.f;
}

// Chunk-summary pool in the dead xc-half of xz (2048 rows x 3072 f32, cols 0..1535).
// 2 fields: 0 = prod (overwritten with init by prefix), 1 = fin.
// rows: ((field*NB+b)*NCHUNK+ch)*16 + d/96  -> max ((1*2+1)*32+31)*16+15 = 2047. fits.
__device__ __forceinline__ size_t pool_addr(int field, int b, int ch, int d, int n) {
    int row = ((field * NB + b) * NCHUNK + ch) * 16 + d / 96;
    int col = (d % 96) * 16 + n;
    return (size_t)row * 3072 + col;
}

// ---------------- f32 -> bf16 conversion (weights) ----------------
__global__ __launch_bounds__(256)
void cvt_bf16_k(const float* __restrict__ in, u16* __restrict__ out, int n4)
{
    int i = blockIdx.x * 256 + threadIdx.x;
    if (i < n4) {
        float4 v = ((const float4*)in)[i];
        unsigned p0 = (unsigned)f2bf(v.x) | ((unsigned)f2bf(v.y) << 16);
        unsigned p1 = (unsigned)f2bf(v.z) | ((unsigned)f2bf(v.w) << 16);
        ((uint2*)out)[i] = make_uint2(p0, p1);
    }
}

// ---------------- RMSNorm: one block per token, bf16 out ----------------
__global__ __launch_bounds__(256)
void rmsnorm_k(const float* __restrict__ in, const float* __restrict__ w,
               u16* __restrict__ out)
{
    int t = blockIdx.x;
    int tid = threadIdx.x;
    const float* row = in + (size_t)t * DM;
    float v0 = row[tid], v1 = row[tid + 256], v2 = row[tid + 512];
    float ss = v0*v0 + v1*v1 + v2*v2;
    #pragma unroll
    for (int m = 32; m >= 1; m >>= 1) ss += __shfl_xor(ss, m, 64);
    __shared__ float red[4];
    if ((tid & 63) == 0) red[tid >> 6] = ss;
    __syncthreads();
    ss = red[0] + red[1] + red[2] + red[3];
    float sc = rsqrtf(ss * (1.f / DM) + 1e-5f);
    u16* orow = out + (size_t)t * DM;
    orow[tid]       = f2bf(v0 * sc * w[tid]);
    orow[tid + 256] = f2bf(v1 * sc * w[tid + 256]);
    orow[tid + 512] = f2bf(v2 * sc * w[tid + 512]);
}

// ---------------- Final RMSNorm on last token only (f32 out) ----------------
__global__ __launch_bounds__(256)
void final_norm_k(const float* __restrict__ h, const float* __restrict__ w,
                  float* __restrict__ out)
{
    int b = blockIdx.x;
    int tid = threadIdx.x;
    const float* row = h + ((size_t)b * NL + (NL - 1)) * DM;
    float v0 = row[tid], v1 = row[tid + 256], v2 = row[tid + 512];
    float ss = v0*v0 + v1*v1 + v2*v2;
    #pragma unroll
    for (int m = 32; m >= 1; m >>= 1) ss += __shfl_xor(ss, m, 64);
    __shared__ float red[4];
    if ((tid & 63) == 0) red[tid >> 6] = ss;
    __syncthreads();
    ss = red[0] + red[1] + red[2] + red[3];
    float sc = rsqrtf(ss * (1.f / DM) + 1e-5f);
    float* orow = out + (size_t)b * DM;
    orow[tid]       = v0 * sc * w[tid];
    orow[tid + 256] = v1 * sc * w[tid + 256];
    orow[tid + 512] = v2 * sc * w[tid + 512];
}

// ---------------- bf16 MFMA NT GEMM ----------------
template<int BM, int BN, int WM, int WN, int EPI>
__global__ __launch_bounds__(256)
void mfma_nt(const u16* __restrict__ A, const u16* __restrict__ B,
             float* __restrict__ C, const float* __restrict__ resid,
             int K, int ldc)
{
    constexpr int BK = 32;
    constexpr int MR = BM / WM / 16;
    constexpr int NR = BN / WN / 16;
    constexpr int ALOADS = BM / 16;
    constexpr int BLOADS = BN / 16;
    constexpr int NLOADS = ALOADS + BLOADS;

    __shared__ alignas(16) u16 lds[2][(BM + BN) * BK];

    const int tid  = threadIdx.x;
    const int lane = tid & 63;
    const int w    = tid >> 6;
    const int bm   = blockIdx.y * BM;
    const int bn   = blockIdx.x * BN;
    const int wm0  = (w / WN) * (BM / WM);
    const int wn0  = (w % WN) * (BN / WN);

    f32x4 acc[MR][NR] = {};

    const int lrow4 = lane >> 2;
    const int lslot = lane & 3;

    auto stage = [&](int buf, int k0) {
        #pragma unroll
        for (int idx = 0; idx < NLOADS; ++idx) {
            if ((idx & 3) != w) continue;
            const bool isA = idx < ALOADS;
            const int rowbase = (isA ? idx : idx - ALOADS) * 16;
            const int r = rowbase + lrow4;
            const int c = (lslot - (r >> 1)) & 3;
            const u16* src = (isA ? A + (size_t)(bm + r) * K
                                  : B + (size_t)(bn + r) * K) + k0 + c * 8;
            u16* dst = &lds[buf][((isA ? 0 : BM) + rowbase) * BK];
            __builtin_amdgcn_global_load_lds(
                (const __attribute__((address_space(1))) void*)src,
                (__attribute__((address_space(3))) void*)dst, 16, 0, 0);
        }
    };

    const int frow   = lane & 15;
    const int fchunk = lane >> 4;
    const int nk = K / BK;

    stage(0, 0);
    for (int kt = 0; kt < nk; ++kt) {
        __syncthreads();
        if (kt + 1 < nk) stage((kt + 1) & 1, (kt + 1) * BK);
        const int buf = kt & 1;
        bf16x8 a[MR], b[NR];
        #pragma unroll
        for (int i = 0; i < MR; ++i) {
            int row = wm0 + i * 16 + frow;
            int ch = (fchunk + (row >> 1)) & 3;
            a[i] = *(const bf16x8*)&lds[buf][row * BK + ch * 8];
        }
        #pragma unroll
        for (int j = 0; j < NR; ++j) {
            int row = wn0 + j * 16 + frow;
            int ch = (fchunk + (row >> 1)) & 3;
            b[j] = *(const bf16x8*)&lds[buf][(BM + row) * BK + ch * 8];
        }
        #pragma unroll
        for (int i = 0; i < MR; ++i)
            #pragma unroll
            for (int j = 0; j < NR; ++j)
                acc[i][j] = __builtin_amdgcn_mfma_f32_16x16x32_bf16(
                                a[i], b[j], acc[i][j], 0, 0, 0);
    }

    #pragma unroll
    for (int i = 0; i < MR; ++i) {
        #pragma unroll
        for (int j = 0; j < NR; ++j) {
            const int col  = bn + wn0 + j * 16 + (lane & 15);
            const int row0 = bm + wm0 + i * 16 + (lane >> 4) * 4;
            #pragma unroll
            for (int r = 0; r < 4; ++r) {
                float v = acc[i][j][r];
                size_t off = (size_t)(row0 + r) * ldc + col;
                if (EPI == 2) v += resid[off];
                C[off] = v;
            }
        }
    }
}

// ---------------- Causal depthwise conv (width 4) + bias + SiLU, bf16 out ----
__global__ __launch_bounds__(256)
void conv_silu_k(const float* __restrict__ xz, const float* __restrict__ cw,
                 const float* __restrict__ cb, u16* __restrict__ xconv)
{
    int t = blockIdx.x;
    int l = t & (NL - 1), b = t >> 10;
    for (int d = threadIdx.x; d < DI; d += 256) {
        float acc = cb[d];
        #pragma unroll
        for (int k = 0; k < DCONV; ++k) {
            int ll = l - (DCONV - 1) + k;
            if (ll >= 0)
                acc = fmaf(xz[((size_t)(b * NL + ll)) * (2*DI) + d], cw[d*DCONV + k], acc);
        }
        float sg = 1.f / (1.f + __expf(-acc));
        xconv[(size_t)t * DI + d] = f2bf(acc * sg);
    }
}

// ---------------- dt_proj (f32 compute) + softplus, bf16 out ----------------
__global__ __launch_bounds__(256)
void gemm_sp_k(const float* __restrict__ A, const float* __restrict__ B,
               u16* __restrict__ C, int M, int N, int K, int lda, int ldb, int ldc,
               const float* __restrict__ bias)
{
    __shared__ __align__(16) float As[16][68];
    __shared__ __align__(16) float Bs[16][68];
    int tid = threadIdx.x;
    int tx = tid & 15, ty = tid >> 4;
    int bm = blockIdx.y * 64, bn = blockIdx.x * 64;
    float acc[4][4] = {};
    for (int k0 = 0; k0 < K; k0 += 16) {
        #pragma unroll
        for (int j = 0; j < 4; ++j) {
            As[tx][ty + 16*j] = A[(size_t)(bm + ty + 16*j) * lda + k0 + tx];
            Bs[tx][ty + 16*j] = B[(size_t)(bn + ty + 16*j) * ldb + k0 + tx];
        }
        __syncthreads();
        #pragma unroll
        for (int kk = 0; kk < 16; ++kk) {
            float4 av = *(const float4*)&As[kk][ty*4];
            float4 bv = *(const float4*)&Bs[kk][tx*4];
            float a[4] = {av.x, av.y, av.z, av.w};
            float b[4] = {bv.x, bv.y, bv.z, bv.w};
            #pragma unroll
            for (int i = 0; i < 4; ++i)
                #pragma unroll
                for (int j = 0; j < 4; ++j)
                    acc[i][j] = fmaf(a[i], b[j], acc[i][j]);
        }
        __syncthreads();
    }
    #pragma unroll
    for (int i = 0; i < 4; ++i) {
        int m = bm + ty*4 + i;
        int n = bn + tx*4;
        float vx = softplus_f(acc[i][0] + bias[n + 0]);
        float vy = softplus_f(acc[i][1] + bias[n + 1]);
        float vz = softplus_f(acc[i][2] + bias[n + 2]);
        float vw = softplus_f(acc[i][3] + bias[n + 3]);
        unsigned p0 = (unsigned)f2bf(vx) | ((unsigned)f2bf(vy) << 16);
        unsigned p1 = (unsigned)f2bf(vz) | ((unsigned)f2bf(vw) << 16);
        *(uint2*)(C + (size_t)m * ldc + n) = make_uint2(p0, p1);
    }
}

// ---------------- Scan pass A: per-chunk local scan -> (prod, fin) ----------
// Block = 64 thr (1 wave): 32 channels x 2 state-halves (8 states/thread).
// Grid (DI/32, NB, NCHUNK).
__global__ __launch_bounds__(64)
void scan_part_k(const u16* __restrict__ delta, const u16* __restrict__ xconv,
                 const float* __restrict__ xdbl, const float* __restrict__ A_log,
                 float* __restrict__ pool)
{
    int lane = threadIdx.x;
    int half = lane >> 5, c32 = lane & 31;
    int d = blockIdx.x * 32 + c32;
    int b = blockIdx.y, ch = blockIdx.z;
    int n0 = half * 8;
    int t0 = b * NL + ch * SCHUNK;

    __shared__ float bs[SCHUNK][16];      // B[t,n] staging, 2KB
    for (int s = lane; s < SCHUNK * 4; s += 64) {
        int st = s >> 2, q = s & 3;
        *(float4*)&bs[st][q * 4] =
            *(const float4*)(xdbl + (size_t)(t0 + st) * 80 + 48 + q * 4);
    }
    __syncthreads();

    float a[8];
    {
        const float* al = A_log + (size_t)d * DS + n0;
        #pragma unroll
        for (int n = 0; n < 8; ++n) a[n] = -__expf(al[n]);
    }
    float s_[8];
    #pragma unroll
    for (int n = 0; n < 8; ++n) s_[n] = 0.f;
    float sdv = 0.f;

    float dvA[4], xcA[4], dvB[4], xcB[4];
    auto ld = [&](int j, float (&dv)[4], float (&xc)[4]) {
        #pragma unroll
        for (int k = 0; k < 4; ++k) {
            int t = t0 + j + k;
            dv[k] = bf2f(delta[(size_t)t * DI + d]);
            xc[k] = bf2f(xconv[(size_t)t * DI + d]);
        }
    };
    auto cp = [&](int j, float (&dv)[4], float (&xc)[4]) {
        #pragma unroll
        for (int k = 0; k < 4; ++k) {
            float u = dv[k] * xc[k];
            sdv += dv[k];
            float bb[8];
            *(float4*)&bb[0] = *(const float4*)&bs[j + k][n0];
            *(float4*)&bb[4] = *(const float4*)&bs[j + k][n0 + 4];
            #pragma unroll
            for (int n = 0; n < 8; ++n) {
                float e = __expf(dv[k] * a[n]);
                s_[n] = fmaf(e, s_[n], u * bb[n]);
            }
        }
    };
    ld(0, dvA, xcA);
    for (int j = 0; j < SCHUNK; j += 8) {
        ld(j + 4, dvB, xcB);
        cp(j, dvA, xcA);
        if (j + 8 < SCHUNK) ld(j + 8, dvA, xcA);
        cp(j + 4, dvB, xcB);
    }

    // prod[n] = exp(a[n] * sum(dv)) — product of per-step decays
    float pr[8];
    #pragma unroll
    for (int n = 0; n < 8; ++n) pr[n] = __expf(sdv * a[n]);

    size_t b0 = pool_addr(0, b, ch, d, n0);
    size_t b1 = pool_addr(1, b, ch, d, n0);
    *(float4*)(pool + b0)     = make_float4(pr[0], pr[1], pr[2], pr[3]);
    *(float4*)(pool + b0 + 4) = make_float4(pr[4], pr[5], pr[6], pr[7]);
    *(float4*)(pool + b1)     = make_float4(s_[0], s_[1], s_[2], s_[3]);
    *(float4*)(pool + b1 + 4) = make_float4(s_[4], s_[5], s_[6], s_[7]);
}

// ---------------- Scan prefix: fold chunk summaries -> init states ----------
// Thread per (d,n). Grid (DI*DS/256, NB). Overwrites prod-slot with init.
__global__ __launch_bounds__(256)
void scan_prefix_k(float* __restrict__ pool)
{
    int dn = blockIdx.x * 256 + threadIdx.x;
    int b = blockIdx.y;
    int d = dn >> 4, n = dn & 15;
    float run = 0.f;
    for (int g = 0; g < NCHUNK; g += 8) {
        float p[8], f[8];
        #pragma unroll
        for (int j = 0; j < 8; ++j) {
            p[j] = pool[pool_addr(0, b, g + j, d, n)];
            f[j] = pool[pool_addr(1, b, g + j, d, n)];
        }
        #pragma unroll
        for (int j = 0; j < 8; ++j) {
            pool[pool_addr(0, b, g + j, d, n)] = run;
            run = fmaf(p[j], run, f[j]);
        }
    }
}

// ---------------- Scan pass B: re-run from init, emit gated y ---------------
// Same decomposition as pass A. PV-sum combined across halves via shfl_xor(32).
__global__ __launch_bounds__(64)
void scan_emit_k(const u16* __restrict__ delta, const u16* __restrict__ xconv,
                 const float* __restrict__ zin,   // xz + DI, row stride 2*DI
                 u16* __restrict__ yout,          // [T, DI] bf16
                 const float* __restrict__ xdbl, const float* __restrict__ A_log,
                 const float* __restrict__ Dp, const float* __restrict__ pool)
{
    int lane = threadIdx.x;
    int half = lane >> 5, c32 = lane & 31;
    int d = blockIdx.x * 32 + c32;
    int b = blockIdx.y, ch = blockIdx.z;
    int n0 = half * 8;
    int t0 = b * NL + ch * SCHUNK;

    __shared__ float bcs[SCHUNK][32];     // B|C staging, 4KB
    for (int s = lane; s < SCHUNK * 8; s += 64) {
        int st = s >> 3, q = s & 7;
        *(float4*)&bcs[st][q * 4] =
            *(const float4*)(xdbl + (size_t)(t0 + st) * 80 + 48 + q * 4);
    }
    __syncthreads();

    float a[8];
    {
        const float* al = A_log + (size_t)d * DS + n0;
        #pragma unroll
        for (int n = 0; n < 8; ++n) a[n] = -__expf(al[n]);
    }
    float dpv = Dp[d];

    float s_[8];
    {
        size_t base = pool_addr(0, b, ch, d, n0);
        float4 v0 = *(const float4*)(pool + base);
        float4 v1 = *(const float4*)(pool + base + 4);
        s_[0]=v0.x; s_[1]=v0.y; s_[2]=v0.z; s_[3]=v0.w;
        s_[4]=v1.x; s_[5]=v1.y; s_[6]=v1.z; s_[7]=v1.w;
    }

    float dvA[4], xcA[4], zvA[4], dvB[4], xcB[4], zvB[4];
    auto ld = [&](int j, float (&dv)[4], float (&xc)[4], float (&zv)[4]) {
        #pragma unroll
        for (int k = 0; k < 4; ++k) {
            int t = t0 + j + k;
            dv[k] = bf2f(delta[(size_t)t * DI + d]);
            xc[k] = bf2f(xconv[(size_t)t * DI + d]);
            zv[k] = zin[(size_t)t * (2*DI) + d];
        }
    };
    auto cp = [&](int j, float (&dv)[4], float (&xc)[4], float (&zv)[4]) {
        #pragma unroll
        for (int k = 0; k < 4; ++k) {
            float u = dv[k] * xc[k];
            float bb[8], cc[8];
            *(float4*)&bb[0] = *(const float4*)&bcs[j + k][n0];
            *(float4*)&bb[4] = *(const float4*)&bcs[j + k][n0 + 4];
            *(float4*)&cc[0] = *(const float4*)&bcs[j + k][16 + n0];
            *(float4*)&cc[4] = *(const float4*)&bcs[j + k][16 + n0 + 4];
            float y0 = 0.f;
            #pragma unroll
            for (int n = 0; n < 8; ++n) {
                float e = __expf(dv[k] * a[n]);
                s_[n] = fmaf(e, s_[n], u * bb[n]);
                y0 = fmaf(s_[n], cc[n], y0);
            }
            float p = y0 + __shfl_xor(y0, 32, 64);
            if (half == 0) {
                float zv_ = zv[k];
                float y = p + xc[k] * dpv;
                y = y * zv_ / (1.f + __expf(-zv_));
                yout[(size_t)(t0 + j + k) * DI + d] = f2bf(y);
            }
        }
    };
    ld(0, dvA, xcA, zvA);
    for (int j = 0; j < SCHUNK; j += 8) {
        ld(j + 4, dvB, xcB, zvB);
        cp(j, dvA, xcA, zvA);
        if (j + 8 < SCHUNK) ld(j + 8, dvA, xcA, zvA);
        cp(j + 4, dvB, xcB, zvB);
    }
}

extern "C" void kernel_launch(void* const* d_in, const int* in_sizes, int n_in,
                              void* d_out, int out_size, void* d_ws, size_t ws_size,
                              hipStream_t stream) {
    const float* x       = (const float*)d_in[0];
    const float* in_w    = (const float*)d_in[1];
    const float* conv_w  = (const float*)d_in[2];
    const float* conv_b  = (const float*)d_in[3];
    const float* xp_w    = (const float*)d_in[4];
    const float* dtp_w   = (const float*)d_in[5];
    const float* dtp_b   = (const float*)d_in[6];
    const float* A_log   = (const float*)d_in[7];
    const float* D_param = (const float*)d_in[8];
    const float* out_w   = (const float*)d_in[9];
    const float* norm_w  = (const float*)d_in[10];
    const float* fnorm_w = (const float*)d_in[11];
    float* out = (float*)d_out;

    // ws layout (61.5 MB total)
    float* ws     = (float*)d_ws;
    float* h      = ws;                                 // [2048,768] f32
    float* xz     = h + (size_t)NTOK * DM;              // [2048,3072] f32 (xc half doubles as scan pool)
    float* xdbl   = xz + (size_t)NTOK * 2 * DI;         // [2048,80] f32
    u16*  hnb     = (u16*)(xdbl + (size_t)NTOK * 80);   // [2048,768] bf16
    u16*  xcbf    = hnb + (size_t)NTOK * DM;            // [2048,1536] bf16
    u16*  ybf     = xcbf + (size_t)NTOK * DI;           // [2048,1536] bf16
    u16*  dyb     = ybf + (size_t)NTOK * DI;            // [2048,1536] bf16 (delta)
    u16*  wbf_in  = dyb + (size_t)NTOK * DI;            // [3072,768] bf16
    u16*  wbf_xp  = wbf_in + (size_t)2 * DI * DM;       // [80,1536] bf16
    u16*  wbf_out = wbf_xp + (size_t)80 * DI;           // [768,1536] bf16

    for (int layer = 0; layer < NLAYERS; ++layer) {
        const float* hin = (layer == 0) ? x : h;
        const float* Alog_l = A_log + (size_t)layer * DI * DS;

        // 0. weight conversion f32 -> bf16
        cvt_bf16_k<<<2304, 256, 0, stream>>>(in_w + (size_t)layer * 2*DI*DM, wbf_in, (2*DI*DM)/4);
        cvt_bf16_k<<<120, 256, 0, stream>>>(xp_w + (size_t)layer * 80*DI, wbf_xp, (80*DI)/4);
        cvt_bf16_k<<<1152, 256, 0, stream>>>(out_w + (size_t)layer * DM*DI, wbf_out, (DM*DI)/4);

        // 1. RMSNorm -> bf16
        rmsnorm_k<<<NTOK, 256, 0, stream>>>(hin, norm_w + layer * DM, hnb);

        // 2. in_proj (bf16 MFMA): xz = hn @ in_w^T  [2048,3072] f32
        mfma_nt<128, 128, 2, 2, 0><<<dim3((2*DI)/128, NTOK/128), 256, 0, stream>>>(
            hnb, wbf_in, xz, nullptr, DM, 2*DI);

        // 3. causal depthwise conv + SiLU -> bf16
        conv_silu_k<<<NTOK, 256, 0, stream>>>(
            xz, conv_w + (size_t)layer * DI * DCONV, conv_b + (size_t)layer * DI, xcbf);

        // 4. x_proj (bf16 MFMA): xdbl = xconv @ xp_w^T  [2048,80] f32
        mfma_nt<64, 80, 4, 1, 0><<<dim3(1, NTOK/64), 256, 0, stream>>>(
            xcbf, wbf_xp, xdbl, nullptr, DI, 80);

        // 5. dt_proj + softplus -> bf16 delta  [2048,1536]
        gemm_sp_k<<<dim3(DI/64, NTOK/64), 256, 0, stream>>>(
            xdbl, dtp_w + (size_t)layer * DI * DTR, dyb,
            NTOK, DI, DTR, 80, DTR, DI, dtp_b + (size_t)layer * DI);

        // 6. selective scan: part -> prefix -> emit (pool in dead xc-half of xz)
        scan_part_k<<<dim3(DI/32, NB, NCHUNK), 64, 0, stream>>>(
            dyb, xcbf, xdbl, Alog_l, xz);
        scan_prefix_k<<<dim3((DI*DS)/256, NB), 256, 0, stream>>>(xz);
        scan_emit_k<<<dim3(DI/32, NB, NCHUNK), 64, 0, stream>>>(
            dyb, xcbf, xz + DI, ybf, xdbl, Alog_l,
            D_param + (size_t)layer * DI, xz);

        // 7. out_proj (bf16 MFMA) + residual: h = hin + y @ out_w^T  [2048,768]
        mfma_nt<64, 128, 2, 2, 2><<<dim3(DM/128, NTOK/64), 256, 0, stream>>>(
            ybf, wbf_out, h, hin, DI, DM);
    }

    // Final RMSNorm on last token of each batch
    final_norm_k<<<NB, 256, 0, stream>>>(h, fnorm_w, out);
}

// Round 7
// 282.412 us; speedup vs baseline: 8.8060x; 1.0483x over previous
//
#include <hip/hip_runtime.h>
#include <math.h>

// Model dims
#define NB 2
#define NL 1024
#define DM 768
#define DI 1536
#define DS 16
#define DCONV 4
#define DTR 48
#define NLAYERS 2
#define NTOK (NB*NL)   // 2048

#define NCHUNK 32
#define SCHUNK 32      // NL / NCHUNK

typedef unsigned short u16;
typedef __attribute__((ext_vector_type(8))) short bf16x8;
typedef __attribute__((ext_vector_type(4))) float f32x4;

__device__ __forceinline__ float softplus_f(float x) {
    return fmaxf(x, 0.f) + log1pf(expf(-fabsf(x)));
}
__device__ __forceinline__ u16 f2bf(float f) {
    union { float f; unsigned u; } x{f};
    unsigned r = x.u + 0x7fff + ((x.u >> 16) & 1);   // RNE
    return (u16)(r >> 16);
}
__device__ __forceinline__ float bf2f(u16 u) {
    union { unsigned u; float f; } x{(unsigned)u << 16};
    return x.f;
}

// Dedicated scan pool: pool[field][b][ch][d][n], field 0 = prod/init, 1 = fin
__device__ __forceinline__ size_t pool_addr(int field, int b, int ch, int d, int n) {
    return (((size_t)(field * NB + b) * NCHUNK + ch) * DI + d) * DS + n;
}

// ---------------- all-weights f32 -> bf16 (one launch) ----------------
#define CVT_N0 (NLAYERS*2*DI*DM/4)
#define CVT_N1 (NLAYERS*(DTR+2*DS)*DI/4)
#define CVT_N2 (NLAYERS*DM*DI/4)
__global__ __launch_bounds__(256)
void cvt_all_k(const float* __restrict__ in_w, const float* __restrict__ xp_w,
               const float* __restrict__ out_w,
               u16* __restrict__ win, u16* __restrict__ wxp, u16* __restrict__ wout)
{
    int i = blockIdx.x * 256 + threadIdx.x;
    const float* src; u16* dst; int j;
    if (i < CVT_N0)                 { src = in_w;  dst = win;  j = i; }
    else if (i < CVT_N0 + CVT_N1)   { src = xp_w;  dst = wxp;  j = i - CVT_N0; }
    else if (i < CVT_N0 + CVT_N1 + CVT_N2) { src = out_w; dst = wout; j = i - CVT_N0 - CVT_N1; }
    else return;
    float4 v = ((const float4*)src)[j];
    unsigned p0 = (unsigned)f2bf(v.x) | ((unsigned)f2bf(v.y) << 16);
    unsigned p1 = (unsigned)f2bf(v.z) | ((unsigned)f2bf(v.w) << 16);
    ((uint2*)dst)[j] = make_uint2(p0, p1);
}

// ---------------- RMSNorm: one block per token, bf16 out ----------------
__global__ __launch_bounds__(256)
void rmsnorm_k(const float* __restrict__ in, const float* __restrict__ w,
               u16* __restrict__ out)
{
    int t = blockIdx.x;
    int tid = threadIdx.x;
    const float* row = in + (size_t)t * DM;
    float v0 = row[tid], v1 = row[tid + 256], v2 = row[tid + 512];
    float ss = v0*v0 + v1*v1 + v2*v2;
    #pragma unroll
    for (int m = 32; m >= 1; m >>= 1) ss += __shfl_xor(ss, m, 64);
    __shared__ float red[4];
    if ((tid & 63) == 0) red[tid >> 6] = ss;
    __syncthreads();
    ss = red[0] + red[1] + red[2] + red[3];
    float sc = rsqrtf(ss * (1.f / DM) + 1e-5f);
    u16* orow = out + (size_t)t * DM;
    orow[tid]       = f2bf(v0 * sc * w[tid]);
    orow[tid + 256] = f2bf(v1 * sc * w[tid + 256]);
    orow[tid + 512] = f2bf(v2 * sc * w[tid + 512]);
}

// ---------------- Final RMSNorm on last token only (f32 out) ----------------
__global__ __launch_bounds__(256)
void final_norm_k(const float* __restrict__ h, const float* __restrict__ w,
                  float* __restrict__ out)
{
    int b = blockIdx.x;
    int tid = threadIdx.x;
    const float* row = h + ((size_t)b * NL + (NL - 1)) * DM;
    float v0 = row[tid], v1 = row[tid + 256], v2 = row[tid + 512];
    float ss = v0*v0 + v1*v1 + v2*v2;
    #pragma unroll
    for (int m = 32; m >= 1; m >>= 1) ss += __shfl_xor(ss, m, 64);
    __shared__ float red[4];
    if ((tid & 63) == 0) red[tid >> 6] = ss;
    __syncthreads();
    ss = red[0] + red[1] + red[2] + red[3];
    float sc = rsqrtf(ss * (1.f / DM) + 1e-5f);
    float* orow = out + (size_t)b * DM;
    orow[tid]       = v0 * sc * w[tid];
    orow[tid + 256] = v1 * sc * w[tid + 256];
    orow[tid + 512] = v2 * sc * w[tid + 512];
}

// ---------------- bf16 MFMA NT GEMM ----------------
// EPI: 0 = f32 store; 2 = f32 + resid; 3 = bf16 store.
template<int BM, int BN, int WM, int WN, int EPI>
__global__ __launch_bounds__(256)
void mfma_nt(const u16* __restrict__ A, const u16* __restrict__ B,
             void* __restrict__ Cv, const float* __restrict__ resid,
             int K, int ldc)
{
    constexpr int BK = 32;
    constexpr int MR = BM / WM / 16;
    constexpr int NR = BN / WN / 16;
    constexpr int ALOADS = BM / 16;
    constexpr int BLOADS = BN / 16;
    constexpr int NLOADS = ALOADS + BLOADS;

    __shared__ alignas(16) u16 lds[2][(BM + BN) * BK];

    const int tid  = threadIdx.x;
    const int lane = tid & 63;
    const int w    = tid >> 6;

    // XCD-aware swizzle (bijective when nwg % 8 == 0)
    int nwg = gridDim.x * gridDim.y;
    int id  = blockIdx.y * gridDim.x + blockIdx.x;
    if ((nwg & 7) == 0) id = (id & 7) * (nwg >> 3) + (id >> 3);
    const int bm = (id / gridDim.x) * BM;
    const int bn = (id % gridDim.x) * BN;

    const int wm0  = (w / WN) * (BM / WM);
    const int wn0  = (w % WN) * (BN / WN);

    f32x4 acc[MR][NR] = {};

    const int lrow4 = lane >> 2;
    const int lslot = lane & 3;

    auto stage = [&](int buf, int k0) {
        #pragma unroll
        for (int idx = 0; idx < NLOADS; ++idx) {
            if ((idx & 3) != w) continue;
            const bool isA = idx < ALOADS;
            const int rowbase = (isA ? idx : idx - ALOADS) * 16;
            const int r = rowbase + lrow4;
            const int c = (lslot - (r >> 1)) & 3;
            const u16* src = (isA ? A + (size_t)(bm + r) * K
                                  : B + (size_t)(bn + r) * K) + k0 + c * 8;
            u16* dst = &lds[buf][((isA ? 0 : BM) + rowbase) * BK];
            __builtin_amdgcn_global_load_lds(
                (const __attribute__((address_space(1))) void*)src,
                (__attribute__((address_space(3))) void*)dst, 16, 0, 0);
        }
    };

    const int frow   = lane & 15;
    const int fchunk = lane >> 4;
    const int nk = K / BK;

    stage(0, 0);
    for (int kt = 0; kt < nk; ++kt) {
        __syncthreads();
        if (kt + 1 < nk) stage((kt + 1) & 1, (kt + 1) * BK);
        const int buf = kt & 1;
        bf16x8 a[MR], b[NR];
        #pragma unroll
        for (int i = 0; i < MR; ++i) {
            int row = wm0 + i * 16 + frow;
            int ch = (fchunk + (row >> 1)) & 3;
            a[i] = *(const bf16x8*)&lds[buf][row * BK + ch * 8];
        }
        #pragma unroll
        for (int j = 0; j < NR; ++j) {
            int row = wn0 + j * 16 + frow;
            int ch = (fchunk + (row >> 1)) & 3;
            b[j] = *(const bf16x8*)&lds[buf][(BM + row) * BK + ch * 8];
        }
        #pragma unroll
        for (int i = 0; i < MR; ++i)
            #pragma unroll
            for (int j = 0; j < NR; ++j)
                acc[i][j] = __builtin_amdgcn_mfma_f32_16x16x32_bf16(
                                a[i], b[j], acc[i][j], 0, 0, 0);
    }

    #pragma unroll
    for (int i = 0; i < MR; ++i) {
        #pragma unroll
        for (int j = 0; j < NR; ++j) {
            const int col  = bn + wn0 + j * 16 + (lane & 15);
            const int row0 = bm + wm0 + i * 16 + (lane >> 4) * 4;
            #pragma unroll
            for (int r = 0; r < 4; ++r) {
                float v = acc[i][j][r];
                size_t off = (size_t)(row0 + r) * ldc + col;
                if (EPI == 3) {
                    ((u16*)Cv)[off] = f2bf(v);
                } else {
                    if (EPI == 2) v += resid[off];
                    ((float*)Cv)[off] = v;
                }
            }
        }
    }
}

// ---------------- Causal depthwise conv (width 4) + bias + SiLU -------------
// xz bf16 [T, 2*DI]; 384 thr x 4 channels; bf16 out.
__global__ __launch_bounds__(384)
void conv_silu_k(const u16* __restrict__ xz, const float* __restrict__ cw,
                 const float* __restrict__ cb, u16* __restrict__ xconv)
{
    int t = blockIdx.x;
    int l = t & (NL - 1), b = t >> 10;
    int d0 = threadIdx.x * 4;

    float acc[4];
    {
        float4 cbv = *(const float4*)(cb + d0);
        acc[0] = cbv.x; acc[1] = cbv.y; acc[2] = cbv.z; acc[3] = cbv.w;
    }
    float wv[16];
    {
        const float4* cwp = (const float4*)(cw + (size_t)d0 * DCONV);
        *(float4*)&wv[0]  = cwp[0];
        *(float4*)&wv[4]  = cwp[1];
        *(float4*)&wv[8]  = cwp[2];
        *(float4*)&wv[12] = cwp[3];
    }
    #pragma unroll
    for (int k = 0; k < DCONV; ++k) {
        int ll = l - (DCONV - 1) + k;
        if (ll < 0) continue;                       // block-uniform
        ushort4 v = *(const ushort4*)(xz + (size_t)(b * NL + ll) * (2*DI) + d0);
        acc[0] = fmaf(bf2f(v.x), wv[0*4 + k], acc[0]);
        acc[1] = fmaf(bf2f(v.y), wv[1*4 + k], acc[1]);
        acc[2] = fmaf(bf2f(v.z), wv[2*4 + k], acc[2]);
        acc[3] = fmaf(bf2f(v.w), wv[3*4 + k], acc[3]);
    }
    ushort4 o;
    {
        float s0 = acc[0] / (1.f + __expf(-acc[0]));
        float s1 = acc[1] / (1.f + __expf(-acc[1]));
        float s2 = acc[2] / (1.f + __expf(-acc[2]));
        float s3 = acc[3] / (1.f + __expf(-acc[3]));
        o.x = f2bf(s0); o.y = f2bf(s1); o.z = f2bf(s2); o.w = f2bf(s3);
    }
    *(ushort4*)(xconv + (size_t)t * DI + d0) = o;
}

// ---------------- dt_proj (f32 compute) + softplus, bf16 out ----------------
__global__ __launch_bounds__(256)
void gemm_sp_k(const float* __restrict__ A, const float* __restrict__ B,
               u16* __restrict__ C, int M, int N, int K, int lda, int ldb, int ldc,
               const float* __restrict__ bias)
{
    __shared__ __align__(16) float As[16][68];
    __shared__ __align__(16) float Bs[16][68];
    int tid = threadIdx.x;
    int tx = tid & 15, ty = tid >> 4;
    int bm = blockIdx.y * 64, bn = blockIdx.x * 64;
    float acc[4][4] = {};
    for (int k0 = 0; k0 < K; k0 += 16) {
        #pragma unroll
        for (int j = 0; j < 4; ++j) {
            As[tx][ty + 16*j] = A[(size_t)(bm + ty + 16*j) * lda + k0 + tx];
            Bs[tx][ty + 16*j] = B[(size_t)(bn + ty + 16*j) * ldb + k0 + tx];
        }
        __syncthreads();
        #pragma unroll
        for (int kk = 0; kk < 16; ++kk) {
            float4 av = *(const float4*)&As[kk][ty*4];
            float4 bv = *(const float4*)&Bs[kk][tx*4];
            float a[4] = {av.x, av.y, av.z, av.w};
            float b[4] = {bv.x, bv.y, bv.z, bv.w};
            #pragma unroll
            for (int i = 0; i < 4; ++i)
                #pragma unroll
                for (int j = 0; j < 4; ++j)
                    acc[i][j] = fmaf(a[i], b[j], acc[i][j]);
        }
        __syncthreads();
    }
    #pragma unroll
    for (int i = 0; i < 4; ++i) {
        int m = bm + ty*4 + i;
        int n = bn + tx*4;
        float vx = softplus_f(acc[i][0] + bias[n + 0]);
        float vy = softplus_f(acc[i][1] + bias[n + 1]);
        float vz = softplus_f(acc[i][2] + bias[n + 2]);
        float vw = softplus_f(acc[i][3] + bias[n + 3]);
        unsigned p0 = (unsigned)f2bf(vx) | ((unsigned)f2bf(vy) << 16);
        unsigned p1 = (unsigned)f2bf(vz) | ((unsigned)f2bf(vw) << 16);
        *(uint2*)(C + (size_t)m * ldc + n) = make_uint2(p0, p1);
    }
}

// ---------------- Scan pass A: per-chunk local scan -> (prod, fin) ----------
// Block = 64 thr (1 wave): 32 channels x 2 state-halves (8 states/thread).
// Grid (DI/32, NB, NCHUNK).
__global__ __launch_bounds__(64)
void scan_part_k(const u16* __restrict__ delta, const u16* __restrict__ xconv,
                 const float* __restrict__ xdbl, const float* __restrict__ A_log,
                 float* __restrict__ pool)
{
    int lane = threadIdx.x;
    int half = lane >> 5, c32 = lane & 31;
    int d = blockIdx.x * 32 + c32;
    int b = blockIdx.y, ch = blockIdx.z;
    int n0 = half * 8;
    int t0 = b * NL + ch * SCHUNK;

    __shared__ float bs[SCHUNK][16];      // B[t,n] staging, 2KB
    for (int s = lane; s < SCHUNK * 4; s += 64) {
        int st = s >> 2, q = s & 3;
        *(float4*)&bs[st][q * 4] =
            *(const float4*)(xdbl + (size_t)(t0 + st) * 80 + 48 + q * 4);
    }
    __syncthreads();

    float a[8];
    {
        const float* al = A_log + (size_t)d * DS + n0;
        #pragma unroll
        for (int n = 0; n < 8; ++n) a[n] = -__expf(al[n]);
    }
    float s_[8];
    #pragma unroll
    for (int n = 0; n < 8; ++n) s_[n] = 0.f;
    float sdv = 0.f;

    float dvA[4], xcA[4], dvB[4], xcB[4];
    auto ld = [&](int j, float (&dv)[4], float (&xc)[4]) {
        #pragma unroll
        for (int k = 0; k < 4; ++k) {
            int t = t0 + j + k;
            dv[k] = bf2f(delta[(size_t)t * DI + d]);
            xc[k] = bf2f(xconv[(size_t)t * DI + d]);
        }
    };
    auto cp = [&](int j, float (&dv)[4], float (&xc)[4]) {
        #pragma unroll
        for (int k = 0; k < 4; ++k) {
            float u = dv[k] * xc[k];
            sdv += dv[k];
            float bb[8];
            *(float4*)&bb[0] = *(const float4*)&bs[j + k][n0];
            *(float4*)&bb[4] = *(const float4*)&bs[j + k][n0 + 4];
            #pragma unroll
            for (int n = 0; n < 8; ++n) {
                float e = __expf(dv[k] * a[n]);
                s_[n] = fmaf(e, s_[n], u * bb[n]);
            }
        }
    };
    ld(0, dvA, xcA);
    for (int j = 0; j < SCHUNK; j += 8) {
        ld(j + 4, dvB, xcB);
        cp(j, dvA, xcA);
        if (j + 8 < SCHUNK) ld(j + 8, dvA, xcA);
        cp(j + 4, dvB, xcB);
    }

    float pr[8];
    #pragma unroll
    for (int n = 0; n < 8; ++n) pr[n] = __expf(sdv * a[n]);

    size_t b0 = pool_addr(0, b, ch, d, n0);
    size_t b1 = pool_addr(1, b, ch, d, n0);
    *(float4*)(pool + b0)     = make_float4(pr[0], pr[1], pr[2], pr[3]);
    *(float4*)(pool + b0 + 4) = make_float4(pr[4], pr[5], pr[6], pr[7]);
    *(float4*)(pool + b1)     = make_float4(s_[0], s_[1], s_[2], s_[3]);
    *(float4*)(pool + b1 + 4) = make_float4(s_[4], s_[5], s_[6], s_[7]);
}

// ---------------- Scan prefix: fold chunk summaries -> init states ----------
__global__ __launch_bounds__(256)
void scan_prefix_k(float* __restrict__ pool)
{
    int dn = blockIdx.x * 256 + threadIdx.x;
    int b = blockIdx.y;
    int d = dn >> 4, n = dn & 15;
    float run = 0.f;
    for (int g = 0; g < NCHUNK; g += 8) {
        float p[8], f[8];
        #pragma unroll
        for (int j = 0; j < 8; ++j) {
            p[j] = pool[pool_addr(0, b, g + j, d, n)];
            f[j] = pool[pool_addr(1, b, g + j, d, n)];
        }
        #pragma unroll
        for (int j = 0; j < 8; ++j) {
            pool[pool_addr(0, b, g + j, d, n)] = run;
            run = fmaf(p[j], run, f[j]);
        }
    }
}

// ---------------- Scan pass B: re-run from init, emit gated y ---------------
__global__ __launch_bounds__(64)
void scan_emit_k(const u16* __restrict__ delta, const u16* __restrict__ xconv,
                 const u16* __restrict__ zin,    // xz + DI, row stride 2*DI, bf16
                 u16* __restrict__ yout,         // [T, DI] bf16
                 const float* __restrict__ xdbl, const float* __restrict__ A_log,
                 const float* __restrict__ Dp, const float* __restrict__ pool)
{
    int lane = threadIdx.x;
    int half = lane >> 5, c32 = lane & 31;
    int d = blockIdx.x * 32 + c32;
    int b = blockIdx.y, ch = blockIdx.z;
    int n0 = half * 8;
    int t0 = b * NL + ch * SCHUNK;

    __shared__ float bcs[SCHUNK][32];     // B|C staging, 4KB
    for (int s = lane; s < SCHUNK * 8; s += 64) {
        int st = s >> 3, q = s & 7;
        *(float4*)&bcs[st][q * 4] =
            *(const float4*)(xdbl + (size_t)(t0 + st) * 80 + 48 + q * 4);
    }
    __syncthreads();

    float a[8];
    {
        const float* al = A_log + (size_t)d * DS + n0;
        #pragma unroll
        for (int n = 0; n < 8; ++n) a[n] = -__expf(al[n]);
    }
    float dpv = Dp[d];

    float s_[8];
    {
        size_t base = pool_addr(0, b, ch, d, n0);
        float4 v0 = *(const float4*)(pool + base);
        float4 v1 = *(const float4*)(pool + base + 4);
        s_[0]=v0.x; s_[1]=v0.y; s_[2]=v0.z; s_[3]=v0.w;
        s_[4]=v1.x; s_[5]=v1.y; s_[6]=v1.z; s_[7]=v1.w;
    }

    float dvA[4], xcA[4], zvA[4], dvB[4], xcB[4], zvB[4];
    auto ld = [&](int j, float (&dv)[4], float (&xc)[4], float (&zv)[4]) {
        #pragma unroll
        for (int k = 0; k < 4; ++k) {
            int t = t0 + j + k;
            dv[k] = bf2f(delta[(size_t)t * DI + d]);
            xc[k] = bf2f(xconv[(size_t)t * DI + d]);
            zv[k] = bf2f(zin[(size_t)t * (2*DI) + d]);
        }
    };
    auto cp = [&](int j, float (&dv)[4], float (&xc)[4], float (&zv)[4]) {
        #pragma unroll
        for (int k = 0; k < 4; ++k) {
            float u = dv[k] * xc[k];
            float bb[8], cc[8];
            *(float4*)&bb[0] = *(const float4*)&bcs[j + k][n0];
            *(float4*)&bb[4] = *(const float4*)&bcs[j + k][n0 + 4];
            *(float4*)&cc[0] = *(const float4*)&bcs[j + k][16 + n0];
            *(float4*)&cc[4] = *(const float4*)&bcs[j + k][16 + n0 + 4];
            float y0 = 0.f;
            #pragma unroll
            for (int n = 0; n < 8; ++n) {
                float e = __expf(dv[k] * a[n]);
                s_[n] = fmaf(e, s_[n], u * bb[n]);
                y0 = fmaf(s_[n], cc[n], y0);
            }
            float p = y0 + __shfl_xor(y0, 32, 64);
            if (half == 0) {
                float zv_ = zv[k];
                float y = p + xc[k] * dpv;
                y = y * zv_ / (1.f + __expf(-zv_));
                yout[(size_t)(t0 + j + k) * DI + d] = f2bf(y);
            }
        }
    };
    ld(0, dvA, xcA, zvA);
    for (int j = 0; j < SCHUNK; j += 8) {
        ld(j + 4, dvB, xcB, zvB);
        cp(j, dvA, xcA, zvA);
        if (j + 8 < SCHUNK) ld(j + 8, dvA, xcA, zvA);
        cp(j + 4, dvB, xcB, zvB);
    }
}

extern "C" void kernel_launch(void* const* d_in, const int* in_sizes, int n_in,
                              void* d_out, int out_size, void* d_ws, size_t ws_size,
                              hipStream_t stream) {
    const float* x       = (const float*)d_in[0];
    const float* in_w    = (const float*)d_in[1];
    const float* conv_w  = (const float*)d_in[2];
    const float* conv_b  = (const float*)d_in[3];
    const float* xp_w    = (const float*)d_in[4];
    const float* dtp_w   = (const float*)d_in[5];
    const float* dtp_b   = (const float*)d_in[6];
    const float* A_log   = (const float*)d_in[7];
    const float* D_param = (const float*)d_in[8];
    const float* out_w   = (const float*)d_in[9];
    const float* norm_w  = (const float*)d_in[10];
    const float* fnorm_w = (const float*)d_in[11];
    float* out = (float*)d_out;

    // ws layout (~69 MB)
    float* ws     = (float*)d_ws;
    float* h      = ws;                                   // [2048,768] f32
    float* xdbl   = h + (size_t)NTOK * DM;                // [2048,80] f32
    float* pool   = xdbl + (size_t)NTOK * 80;             // [2][NB][NCHUNK][DI][DS] f32
    u16*  xz      = (u16*)(pool + (size_t)2*NB*NCHUNK*DI*DS);  // [2048,3072] bf16
    u16*  hnb     = xz + (size_t)NTOK * 2 * DI;           // [2048,768] bf16
    u16*  xcbf    = hnb + (size_t)NTOK * DM;              // [2048,1536] bf16
    u16*  ybf     = xcbf + (size_t)NTOK * DI;             // [2048,1536] bf16
    u16*  dyb     = ybf + (size_t)NTOK * DI;              // [2048,1536] bf16 (delta)
    u16*  wbf_in  = dyb + (size_t)NTOK * DI;              // [2,3072,768] bf16
    u16*  wbf_xp  = wbf_in + (size_t)NLAYERS * 2*DI*DM;   // [2,80,1536] bf16
    u16*  wbf_out = wbf_xp + (size_t)NLAYERS * 80*DI;     // [2,768,1536] bf16

    // 0. all weight conversions, one launch, both layers
    cvt_all_k<<<(CVT_N0 + CVT_N1 + CVT_N2 + 255) / 256, 256, 0, stream>>>(
        in_w, xp_w, out_w, wbf_in, wbf_xp, wbf_out);

    for (int layer = 0; layer < NLAYERS; ++layer) {
        const float* hin = (layer == 0) ? x : h;
        const float* Alog_l = A_log + (size_t)layer * DI * DS;
        const u16* win_l  = wbf_in  + (size_t)layer * 2*DI*DM;
        const u16* wxp_l  = wbf_xp  + (size_t)layer * 80*DI;
        const u16* wout_l = wbf_out + (size_t)layer * DM*DI;

        // 1. RMSNorm -> bf16
        rmsnorm_k<<<NTOK, 256, 0, stream>>>(hin, norm_w + layer * DM, hnb);

        // 2. in_proj (bf16 MFMA): xz = hn @ in_w^T  [2048,3072] bf16
        mfma_nt<128, 128, 2, 2, 3><<<dim3((2*DI)/128, NTOK/128), 256, 0, stream>>>(
            hnb, win_l, xz, nullptr, DM, 2*DI);

        // 3. causal depthwise conv + SiLU -> bf16
        conv_silu_k<<<NTOK, 384, 0, stream>>>(
            xz, conv_w + (size_t)layer * DI * DCONV, conv_b + (size_t)layer * DI, xcbf);

        // 4. x_proj (bf16 MFMA): xdbl = xconv @ xp_w^T  [2048,80] f32
        mfma_nt<64, 80, 4, 1, 0><<<dim3(1, NTOK/64), 256, 0, stream>>>(
            xcbf, wxp_l, xdbl, nullptr, DI, 80);

        // 5. dt_proj + softplus -> bf16 delta  [2048,1536]
        gemm_sp_k<<<dim3(DI/64, NTOK/64), 256, 0, stream>>>(
            xdbl, dtp_w + (size_t)layer * DI * DTR, dyb,
            NTOK, DI, DTR, 80, DTR, DI, dtp_b + (size_t)layer * DI);

        // 6. selective scan: part -> prefix -> emit
        scan_part_k<<<dim3(DI/32, NB, NCHUNK), 64, 0, stream>>>(
            dyb, xcbf, xdbl, Alog_l, pool);
        scan_prefix_k<<<dim3((DI*DS)/256, NB), 256, 0, stream>>>(pool);
        scan_emit_k<<<dim3(DI/32, NB, NCHUNK), 64, 0, stream>>>(
            dyb, xcbf, xz + DI, ybf, xdbl, Alog_l,
            D_param + (size_t)layer * DI, pool);

        // 7. out_proj (bf16 MFMA) + residual: h = hin + y @ out_w^T  [2048,768]
        mfma_nt<64, 128, 2, 2, 2><<<dim3(DM/128, NTOK/64), 256, 0, stream>>>(
            ybf, wout_l, h, hin, DI, DM);
    }

    // Final RMSNorm on last token of each batch
    final_norm_k<<<NB, 256, 0, stream>>>(h, fnorm_w, out);
}